// Round 1
// baseline (427.723 us; speedup 1.0000x reference)
//
#include <hip/hip_runtime.h>
#include <hip/hip_bf16.h>

typedef __bf16 bf16x8 __attribute__((ext_vector_type(8)));
typedef __bf16 bf16x4 __attribute__((ext_vector_type(4)));
typedef float  f32x4  __attribute__((ext_vector_type(4)));

#define MFMA16(a, b, c) __builtin_amdgcn_mfma_f32_16x16x32_bf16((a), (b), (c), 0, 0, 0)

constexpr int CB = 2, CH = 160, CW = 160, CC = 192, CHEADS = 6, CD = 32;
constexpr int CWS = 16, COWS = 24, CPAD = 4, CNWIN = 100;
constexpr int CNQ = 256, CNKV = 576, CPH = 168;
constexpr float CSCALE = 0.17677669529663687f; // 32^-0.5

// ---------------------------------------------------------------------------
// Kernel C: expand bias_table[rpi] into MFMA-tile layout [head][qt][kt][lane][4]
// ---------------------------------------------------------------------------
__global__ __launch_bounds__(256)
void bias_expand_k(const int* __restrict__ rpi, const float* __restrict__ tab,
                   __bf16* __restrict__ bt)
{
    int idx = blockIdx.x * 256 + threadIdx.x;   // 6*16*36*64 = 221184 = 864*256
    int lane = idx & 63;
    int rest = idx >> 6;
    int ktl = rest % 36; rest /= 36;
    int qtl = rest & 15;
    int head = rest >> 4;
#pragma unroll
    for (int r = 0; r < 4; ++r) {
        int q = qtl * 16 + (lane >> 4) * 4 + r;
        int k = ktl * 16 + (lane & 15);
        int ri = rpi[q * CNKV + k];
        bt[(long)idx * 4 + r] = (__bf16)tab[ri * CHEADS + head];
    }
}

// ---------------------------------------------------------------------------
// Generic MFMA GEMM. MODE 0: x -> Q(bf16, scaled, window layout) + G(fp32)
//                    MODE 1: x_pad -> KV(bf16, padded image layout)
//                    MODE 2: Y(bf16, window layout) -> out(fp32, image layout)
// Tile: BM=64, BN=64, BK=32, 256 threads (4 waves, each a 32x32 quadrant).
// ---------------------------------------------------------------------------
template <int MODE>
__global__ __launch_bounds__(256)
void gemm_k(const float* __restrict__ xin, const __bf16* __restrict__ yin,
            const float* __restrict__ w0, const float* __restrict__ w1,
            const float* __restrict__ b0, const float* __restrict__ b1,
            __bf16* __restrict__ obf, float* __restrict__ of)
{
    __shared__ __bf16 As[64][40];
    __shared__ __bf16 Bt[64][40];

    const int t = threadIdx.x;
    const int lane = t & 63, wv = t >> 6;
    const int bm = blockIdx.x, bn = blockIdx.y;
    const int l15 = lane & 15, l4 = lane >> 4;

    // A staging: thread -> (row, 8-elem segment)
    const int arow = t >> 2, aseg = t & 3;
    const int m_st = bm * 64 + arow;
    long aoff = 0;
    bool avalid = true;
    if (MODE == 0) {
        int win = m_st >> 8, q = m_st & 255;
        int bb = win / 100, wr = win % 100, wy = wr / 10, wx = wr % 10;
        int y = wy * 16 + (q >> 4), xx = wx * 16 + (q & 15);
        aoff = ((long)((bb * CH + y) * CW + xx)) * CC;
    } else if (MODE == 1) {
        int bb = m_st / (CPH * CPH), r = m_st % (CPH * CPH);
        int py = r / CPH, px = r % CPH;
        int y = py - CPAD, xx = px - CPAD;
        avalid = ((unsigned)y < (unsigned)CH) && ((unsigned)xx < (unsigned)CW);
        aoff = avalid ? ((long)((bb * CH + y) * CW + xx)) * CC : 0;
    } else {
        aoff = (long)m_st * CC;
    }

    // B staging source
    const int bkr = t >> 3, bcs = t & 7;
    const float* wsrc; int ldw, cbase;
    if (MODE == 0) {
        if (bn < 3) { wsrc = w0; ldw = 192; cbase = bn * 64; }
        else        { wsrc = w1; ldw = 192; cbase = (bn - 3) * 64; }
    } else if (MODE == 1) { wsrc = w0; ldw = 384; cbase = bn * 64; }
    else                  { wsrc = w0; ldw = 192; cbase = bn * 64; }

    const int qm = (wv >> 1) * 32, qn = (wv & 1) * 32;
    f32x4 acc[2][2];
#pragma unroll
    for (int i = 0; i < 2; ++i)
#pragma unroll
        for (int j = 0; j < 2; ++j) acc[i][j] = f32x4{0.f, 0.f, 0.f, 0.f};

    for (int kt = 0; kt < 6; ++kt) {
        const int k0 = kt * 32;
        __syncthreads();
        // ---- A stage ----
        if (MODE == 2) {
            bf16x8 v = *(const bf16x8*)(yin + aoff + k0 + aseg * 8);
            *(bf16x8*)&As[arow][aseg * 8] = v;
        } else {
            __bf16* d = &As[arow][aseg * 8];
            if (avalid) {
                const float* src = xin + aoff + k0 + aseg * 8;
                float4 v0 = *(const float4*)(src);
                float4 v1 = *(const float4*)(src + 4);
                d[0] = (__bf16)v0.x; d[1] = (__bf16)v0.y;
                d[2] = (__bf16)v0.z; d[3] = (__bf16)v0.w;
                d[4] = (__bf16)v1.x; d[5] = (__bf16)v1.y;
                d[6] = (__bf16)v1.z; d[7] = (__bf16)v1.w;
            } else {
#pragma unroll
                for (int j = 0; j < 8; ++j) d[j] = (__bf16)0.f;
            }
        }
        // ---- B stage (transpose into Bt[n][k]) ----
        {
            const float* src = wsrc + (long)(k0 + bkr) * ldw + cbase + bcs * 8;
            float4 u0 = *(const float4*)(src);
            float4 u1 = *(const float4*)(src + 4);
            Bt[bcs * 8 + 0][bkr] = (__bf16)u0.x; Bt[bcs * 8 + 1][bkr] = (__bf16)u0.y;
            Bt[bcs * 8 + 2][bkr] = (__bf16)u0.z; Bt[bcs * 8 + 3][bkr] = (__bf16)u0.w;
            Bt[bcs * 8 + 4][bkr] = (__bf16)u1.x; Bt[bcs * 8 + 5][bkr] = (__bf16)u1.y;
            Bt[bcs * 8 + 6][bkr] = (__bf16)u1.z; Bt[bcs * 8 + 7][bkr] = (__bf16)u1.w;
        }
        __syncthreads();
        // ---- MFMA ----
        bf16x8 af[2], bfr[2];
#pragma unroll
        for (int mi = 0; mi < 2; ++mi)
            af[mi] = *(const bf16x8*)&As[qm + mi * 16 + l15][l4 * 8];
#pragma unroll
        for (int ni = 0; ni < 2; ++ni)
            bfr[ni] = *(const bf16x8*)&Bt[qn + ni * 16 + l15][l4 * 8];
#pragma unroll
        for (int mi = 0; mi < 2; ++mi)
#pragma unroll
            for (int ni = 0; ni < 2; ++ni)
                acc[mi][ni] = MFMA16(af[mi], bfr[ni], acc[mi][ni]);
    }

    // ---- epilogue ----
#pragma unroll
    for (int mi = 0; mi < 2; ++mi) {
#pragma unroll
        for (int ni = 0; ni < 2; ++ni) {
#pragma unroll
            for (int r = 0; r < 4; ++r) {
                int row = bm * 64 + qm + mi * 16 + l4 * 4 + r;
                int col = bn * 64 + qn + ni * 16 + l15;
                float val = acc[mi][ni][r];
                if (MODE == 0) {
                    if (bn < 3)
                        obf[(long)row * CC + col] = (__bf16)((val + b0[col]) * CSCALE);
                    else
                        of[(long)row * CC + (col - 192)] = val + b1[col - 192];
                } else if (MODE == 1) {
                    obf[(long)row * 384 + col] = (__bf16)(val + b0[col]);
                } else {
                    int win = row >> 8, q = row & 255;
                    int bb = win / 100, wr = win % 100, wy = wr / 10, wx = wr % 10;
                    int y = wy * 16 + (q >> 4), xx = wx * 16 + (q & 15);
                    of[((long)((bb * CH + y) * CW + xx)) * CC + col] = val + b0[col];
                }
            }
        }
    }
}

// ---------------------------------------------------------------------------
// Attention kernel: 1 block = (window, head); 4 waves x 64 q-rows; flash over
// 9 chunks of 64 kv positions. d=32 -> one K=32 MFMA per 16x16 tile.
// ---------------------------------------------------------------------------
__global__ __launch_bounds__(256)
void attn_k(const __bf16* __restrict__ Q, const __bf16* __restrict__ KV,
            const float* __restrict__ G, const __bf16* __restrict__ BT,
            __bf16* __restrict__ Y)
{
    __shared__ __bf16 Ks[64][40];     // K chunk [kv][d]
    __shared__ __bf16 Vt[32][72];     // V chunk transposed [d][kv]
    __shared__ __bf16 Ps[4][64][72];  // per-wave P tile [q][kv]

    const int head = blockIdx.x, win = blockIdx.y;
    const int bb = win / 100, wr = win % 100, wy = wr / 10, wx = wr % 10;
    const int t = threadIdx.x, lane = t & 63, wv = t >> 6;
    const int l15 = lane & 15, l4 = lane >> 4;

    // Q fragments (rows wv*64 .. +64), pre-scaled bf16
    bf16x8 qf[4];
    const __bf16* qbase = Q + ((long)win * CNQ + wv * 64) * CC + head * CD;
#pragma unroll
    for (int m = 0; m < 4; ++m)
        qf[m] = *(const bf16x8*)(qbase + (m * 16 + l15) * CC + l4 * 8);

    const f32x4 z4 = {0.f, 0.f, 0.f, 0.f};
    f32x4 o[4][2];
    float mrun[4][4], srun[4][4];
#pragma unroll
    for (int m = 0; m < 4; ++m) {
#pragma unroll
        for (int no = 0; no < 2; ++no) o[m][no] = z4;
#pragma unroll
        for (int r = 0; r < 4; ++r) { mrun[m][r] = -1e30f; srun[m][r] = 0.f; }
    }

    const int si = t >> 2, sseg = t & 3;

    for (int ch = 0; ch < 9; ++ch) {
        __syncthreads();
        // ---- stage K chunk + transposed V chunk ----
        {
            int kvp = ch * 64 + si;
            int oy = kvp / 24, ox = kvp - oy * 24;
            int py = wy * 16 + oy, px = wx * 16 + ox;
            const __bf16* kvrow =
                KV + ((long)((bb * CPH + py) * CPH + px)) * 384 + head * CD + sseg * 8;
            bf16x8 kv8 = *(const bf16x8*)(kvrow);
            bf16x8 vv8 = *(const bf16x8*)(kvrow + CC);
            *(bf16x8*)&Ks[si][sseg * 8] = kv8;
#pragma unroll
            for (int j = 0; j < 8; ++j) Vt[sseg * 8 + j][si] = vv8[j];
        }
        __syncthreads();

        // ---- scores ----
        bf16x8 kf[4];
#pragma unroll
        for (int n = 0; n < 4; ++n)
            kf[n] = *(const bf16x8*)&Ks[n * 16 + l15][l4 * 8];

        float msk[4];
#pragma unroll
        for (int n = 0; n < 4; ++n) {
            int kp = ch * 64 + n * 16 + l15;
            int oy = kp / 24, ox = kp - oy * 24;
            int yy = wy * 16 + oy - CPAD, xx = wx * 16 + ox - CPAD;
            msk[n] = (((unsigned)yy < (unsigned)CH) && ((unsigned)xx < (unsigned)CW))
                         ? 0.f : -100.f;
        }

        f32x4 sc[4][4];
#pragma unroll
        for (int m = 0; m < 4; ++m)
#pragma unroll
            for (int n = 0; n < 4; ++n)
                sc[m][n] = MFMA16(qf[m], kf[n], z4);

        // bias + mask
#pragma unroll
        for (int m = 0; m < 4; ++m) {
#pragma unroll
            for (int n = 0; n < 4; ++n) {
                const __bf16* bp =
                    BT + ((long)(((head * 16 + wv * 4 + m) * 36 + ch * 4 + n) * 64 + lane)) * 4;
                bf16x4 bv = *(const bf16x4*)bp;
#pragma unroll
                for (int r = 0; r < 4; ++r)
                    sc[m][n][r] += (float)bv[r] + msk[n];
            }
        }

        // ---- online softmax (row = l4*4+r within 16-lane group) ----
#pragma unroll
        for (int m = 0; m < 4; ++m) {
#pragma unroll
            for (int r = 0; r < 4; ++r) {
                float cm = fmaxf(fmaxf(sc[m][0][r], sc[m][1][r]),
                                 fmaxf(sc[m][2][r], sc[m][3][r]));
                cm = fmaxf(cm, __shfl_xor(cm, 1));
                cm = fmaxf(cm, __shfl_xor(cm, 2));
                cm = fmaxf(cm, __shfl_xor(cm, 4));
                cm = fmaxf(cm, __shfl_xor(cm, 8));
                float mnew = fmaxf(mrun[m][r], cm);
                float fac = __expf(mrun[m][r] - mnew);
                mrun[m][r] = mnew;
                float ps = 0.f;
#pragma unroll
                for (int n = 0; n < 4; ++n) {
                    float p = __expf(sc[m][n][r] - mnew);
                    sc[m][n][r] = p;
                    ps += p;
                }
                ps += __shfl_xor(ps, 1);
                ps += __shfl_xor(ps, 2);
                ps += __shfl_xor(ps, 4);
                ps += __shfl_xor(ps, 8);
                srun[m][r] = srun[m][r] * fac + ps;
                o[m][0][r] *= fac;
                o[m][1][r] *= fac;
            }
        }

        // ---- P -> LDS (bf16) ----
#pragma unroll
        for (int m = 0; m < 4; ++m)
#pragma unroll
            for (int n = 0; n < 4; ++n)
#pragma unroll
                for (int r = 0; r < 4; ++r)
                    Ps[wv][m * 16 + l4 * 4 + r][n * 16 + l15] = (__bf16)sc[m][n][r];
        __syncthreads();

        // ---- PV ----
        bf16x8 vf[2][2];
#pragma unroll
        for (int ks = 0; ks < 2; ++ks)
#pragma unroll
            for (int no = 0; no < 2; ++no)
                vf[ks][no] = *(const bf16x8*)&Vt[no * 16 + l15][ks * 32 + l4 * 8];
#pragma unroll
        for (int m = 0; m < 4; ++m) {
#pragma unroll
            for (int ks = 0; ks < 2; ++ks) {
                bf16x8 pa = *(const bf16x8*)&Ps[wv][m * 16 + l15][ks * 32 + l4 * 8];
#pragma unroll
                for (int no = 0; no < 2; ++no)
                    o[m][no] = MFMA16(pa, vf[ks][no], o[m][no]);
            }
        }
    }

    // ---- epilogue: normalize, gate, store bf16 (window layout) ----
#pragma unroll
    for (int m = 0; m < 4; ++m) {
#pragma unroll
        for (int no = 0; no < 2; ++no) {
#pragma unroll
            for (int r = 0; r < 4; ++r) {
                int q = wv * 64 + m * 16 + l4 * 4 + r;
                int col = no * 16 + l15;
                float val = o[m][no][r] / srun[m][r];
                long gi = ((long)win * CNQ + q) * CC + head * CD + col;
                val *= G[gi];
                Y[gi] = (__bf16)val;
            }
        }
    }
}

// ---------------------------------------------------------------------------
extern "C" void kernel_launch(void* const* d_in, const int* in_sizes, int n_in,
                              void* d_out, int out_size, void* d_ws, size_t ws_size,
                              hipStream_t stream)
{
    (void)in_sizes; (void)n_in; (void)out_size; (void)ws_size;
    const float* x    = (const float*)d_in[0];
    const int*   rpi  = (const int*)  d_in[1];
    // d_in[2] = attn_mask (recomputed analytically)
    const float* q_w  = (const float*)d_in[3];
    const float* q_b  = (const float*)d_in[4];
    const float* kv_w = (const float*)d_in[5];
    const float* kv_b = (const float*)d_in[6];
    const float* btab = (const float*)d_in[7];
    const float* g_w  = (const float*)d_in[8];
    const float* g_b  = (const float*)d_in[9];
    const float* p_w  = (const float*)d_in[10];
    const float* p_b  = (const float*)d_in[11];
    float* out = (float*)d_out;

    char* ws = (char*)d_ws;
    __bf16* Qb  = (__bf16*)(ws);                 // 200*256*192 bf16 = 19,660,800 B
    __bf16* KVb = (__bf16*)(ws + 19660800);      // 2*168*168*384 bf16 = 43,352,064 B
    float*  Gf  = (float*)(ws + 63012864);       // 51200*192 f32 = 39,321,600 B
    __bf16* Yb  = (__bf16*)(ws + 102334464);     // 19,660,800 B
    __bf16* BT  = (__bf16*)(ws + 121995264);     // 6*16*36*64*4 bf16 = 1,769,472 B

    bias_expand_k<<<864, 256, 0, stream>>>(rpi, btab, BT);
    gemm_k<0><<<dim3(800, 6), 256, 0, stream>>>(x, nullptr, q_w, g_w, q_b, g_b, Qb, Gf);
    gemm_k<1><<<dim3(882, 6), 256, 0, stream>>>(x, nullptr, kv_w, nullptr, kv_b, nullptr, KVb, nullptr);
    attn_k<<<dim3(6, 200), 256, 0, stream>>>(Qb, KVb, Gf, BT, Yb);
    gemm_k<2><<<dim3(800, 3), 256, 0, stream>>>(nullptr, Yb, p_w, nullptr, p_b, nullptr, nullptr, out);
}

// Round 3
// 259.094 us; speedup vs baseline: 1.6508x; 1.6508x over previous
//
#include <hip/hip_runtime.h>
#include <hip/hip_bf16.h>
#include <stdint.h>

typedef __bf16 bf16x8 __attribute__((ext_vector_type(8)));
typedef __bf16 bf16x4 __attribute__((ext_vector_type(4)));
typedef float  f32x4  __attribute__((ext_vector_type(4)));
typedef float  f32x16 __attribute__((ext_vector_type(16)));
typedef uint32_t u32;

#define MFMA16(a, b, c) __builtin_amdgcn_mfma_f32_16x16x32_bf16((a), (b), (c), 0, 0, 0)
#define MFMA32(a, b, c) __builtin_amdgcn_mfma_f32_32x32x16_bf16((a), (b), (c), 0, 0, 0)

constexpr int CB = 2, CH = 160, CW = 160, CC = 192, CHEADS = 6, CD = 32;
constexpr int CWS = 16, COWS = 24, CPAD = 4;
constexpr int CNQ = 256, CNKV = 576, CPH = 168;
constexpr float LOG2E = 1.44269504088896340736f;
constexpr float QSCALE_L2E = 0.17677669529663687f * 1.44269504088896340736f;
constexpr float MASK_L2E = -100.0f * 1.44269504088896340736f;

static __device__ __forceinline__ u32 pack_bf16(float lo, float hi) {
    __bf16 a = (__bf16)lo, b = (__bf16)hi;
    u32 ua = (u32)__builtin_bit_cast(unsigned short, a);
    u32 ub = (u32)__builtin_bit_cast(unsigned short, b);
    return ua | (ub << 16);
}

// ---------------------------------------------------------------------------
// Bias+mask table: BT[cls 9][head 6][qtg 8][ktg 18][lane 64][reg 16] bf16.
// Value = bias_table[rpi[q][kv]][head]*log2e + (valid(cls,kv) ? 0 : -100*log2e)
// where q = qtg*32 + (lane&31), kv = ktg*32 + (r&3) + 8*(r>>2) + 4*(lane>>5)
// (the verified 32x32 MFMA C/D row mapping).
// ---------------------------------------------------------------------------
__global__ __launch_bounds__(256)
void bias2_k(const int* __restrict__ rpi, const float* __restrict__ tab,
             __bf16* __restrict__ bt)
{
    int idx = blockIdx.x * 256 + threadIdx.x;  // 6*8*18*64 = 55296
    int lane = idx & 63;
    int rest = idx >> 6;
    int ktg = rest % 18; rest /= 18;
    int qtg = rest & 7;
    int head = rest >> 3;
    int l31 = lane & 31, hi = lane >> 5;
    int q = qtg * 32 + l31;

    float bv[16];
#pragma unroll
    for (int g = 0; g < 4; ++g) {
        int4 ri = *(const int4*)(rpi + q * CNKV + ktg * 32 + 4 * hi + g * 8);
        bv[g * 4 + 0] = tab[ri.x * CHEADS + head] * LOG2E;
        bv[g * 4 + 1] = tab[ri.y * CHEADS + head] * LOG2E;
        bv[g * 4 + 2] = tab[ri.z * CHEADS + head] * LOG2E;
        bv[g * 4 + 3] = tab[ri.w * CHEADS + head] * LOG2E;
    }
#pragma unroll
    for (int cls = 0; cls < 9; ++cls) {
        int cy = cls / 3, cx = cls % 3;
        __bf16 o16[16];
#pragma unroll
        for (int r = 0; r < 16; ++r) {
            int kv = ktg * 32 + (r & 3) + 8 * (r >> 2) + 4 * hi;
            int oy = kv / 24, ox = kv - oy * 24;
            bool vy = (cy == 0) ? (oy >= 4) : ((cy == 2) ? (oy < 20) : true);
            bool vx = (cx == 0) ? (ox >= 4) : ((cx == 2) ? (ox < 20) : true);
            o16[r] = (__bf16)((vy && vx) ? bv[r] : (bv[r] + MASK_L2E));
        }
        __bf16* dst = bt + ((long)cls * 55296 + idx) * 16;
        *(bf16x8*)dst = *(bf16x8*)&o16[0];
        *(bf16x8*)(dst + 8) = *(bf16x8*)&o16[8];
    }
}

// ---------------------------------------------------------------------------
// Generic MFMA GEMM. MODE 0: x -> Q(bf16, scaled*log2e) + Gates(bf16)
//                    MODE 1: x_pad -> KV(bf16, padded image layout)
//                    MODE 2: Y(bf16, window layout) -> out(fp32, image layout)
// Tile: BM=64, BN=64, BK=32, 256 threads (4 waves, each a 32x32 quadrant).
// ---------------------------------------------------------------------------
template <int MODE>
__global__ __launch_bounds__(256)
void gemm_k(const float* __restrict__ xin, const __bf16* __restrict__ yin,
            const float* __restrict__ w0, const float* __restrict__ w1,
            const float* __restrict__ b0, const float* __restrict__ b1,
            __bf16* __restrict__ obf, __bf16* __restrict__ obf2,
            float* __restrict__ of)
{
    __shared__ __bf16 As[64][40];
    __shared__ __bf16 Bt[64][40];

    const int t = threadIdx.x;
    const int lane = t & 63, wv = t >> 6;
    const int bm = blockIdx.x, bn = blockIdx.y;
    const int l15 = lane & 15, l4 = lane >> 4;

    const int arow = t >> 2, aseg = t & 3;
    const int m_st = bm * 64 + arow;
    long aoff = 0;
    bool avalid = true;
    if (MODE == 0) {
        int win = m_st >> 8, q = m_st & 255;
        int bb = win / 100, wr = win % 100, wy = wr / 10, wx = wr % 10;
        int y = wy * 16 + (q >> 4), xx = wx * 16 + (q & 15);
        aoff = ((long)((bb * CH + y) * CW + xx)) * CC;
    } else if (MODE == 1) {
        int bb = m_st / (CPH * CPH), r = m_st % (CPH * CPH);
        int py = r / CPH, px = r % CPH;
        int y = py - CPAD, xx = px - CPAD;
        avalid = ((unsigned)y < (unsigned)CH) && ((unsigned)xx < (unsigned)CW);
        aoff = avalid ? ((long)((bb * CH + y) * CW + xx)) * CC : 0;
    } else {
        aoff = (long)m_st * CC;
    }

    const int bkr = t >> 3, bcs = t & 7;
    const float* wsrc; int ldw, cbase;
    if (MODE == 0) {
        if (bn < 3) { wsrc = w0; ldw = 192; cbase = bn * 64; }
        else        { wsrc = w1; ldw = 192; cbase = (bn - 3) * 64; }
    } else if (MODE == 1) { wsrc = w0; ldw = 384; cbase = bn * 64; }
    else                  { wsrc = w0; ldw = 192; cbase = bn * 64; }

    const int qm = (wv >> 1) * 32, qn = (wv & 1) * 32;
    f32x4 acc[2][2];
#pragma unroll
    for (int i = 0; i < 2; ++i)
#pragma unroll
        for (int j = 0; j < 2; ++j) acc[i][j] = f32x4{0.f, 0.f, 0.f, 0.f};

    for (int kt = 0; kt < 6; ++kt) {
        const int k0 = kt * 32;
        __syncthreads();
        if (MODE == 2) {
            bf16x8 v = *(const bf16x8*)(yin + aoff + k0 + aseg * 8);
            *(bf16x8*)&As[arow][aseg * 8] = v;
        } else {
            __bf16* d = &As[arow][aseg * 8];
            if (avalid) {
                const float* src = xin + aoff + k0 + aseg * 8;
                float4 v0 = *(const float4*)(src);
                float4 v1 = *(const float4*)(src + 4);
                d[0] = (__bf16)v0.x; d[1] = (__bf16)v0.y;
                d[2] = (__bf16)v0.z; d[3] = (__bf16)v0.w;
                d[4] = (__bf16)v1.x; d[5] = (__bf16)v1.y;
                d[6] = (__bf16)v1.z; d[7] = (__bf16)v1.w;
            } else {
#pragma unroll
                for (int j = 0; j < 8; ++j) d[j] = (__bf16)0.f;
            }
        }
        {
            const float* src = wsrc + (long)(k0 + bkr) * ldw + cbase + bcs * 8;
            float4 u0 = *(const float4*)(src);
            float4 u1 = *(const float4*)(src + 4);
            Bt[bcs * 8 + 0][bkr] = (__bf16)u0.x; Bt[bcs * 8 + 1][bkr] = (__bf16)u0.y;
            Bt[bcs * 8 + 2][bkr] = (__bf16)u0.z; Bt[bcs * 8 + 3][bkr] = (__bf16)u0.w;
            Bt[bcs * 8 + 4][bkr] = (__bf16)u1.x; Bt[bcs * 8 + 5][bkr] = (__bf16)u1.y;
            Bt[bcs * 8 + 6][bkr] = (__bf16)u1.z; Bt[bcs * 8 + 7][bkr] = (__bf16)u1.w;
        }
        __syncthreads();
        bf16x8 af[2], bfr[2];
#pragma unroll
        for (int mi = 0; mi < 2; ++mi)
            af[mi] = *(const bf16x8*)&As[qm + mi * 16 + l15][l4 * 8];
#pragma unroll
        for (int ni = 0; ni < 2; ++ni)
            bfr[ni] = *(const bf16x8*)&Bt[qn + ni * 16 + l15][l4 * 8];
#pragma unroll
        for (int mi = 0; mi < 2; ++mi)
#pragma unroll
            for (int ni = 0; ni < 2; ++ni)
                acc[mi][ni] = MFMA16(af[mi], bfr[ni], acc[mi][ni]);
    }

#pragma unroll
    for (int mi = 0; mi < 2; ++mi) {
#pragma unroll
        for (int ni = 0; ni < 2; ++ni) {
#pragma unroll
            for (int r = 0; r < 4; ++r) {
                int row = bm * 64 + qm + mi * 16 + l4 * 4 + r;
                int col = bn * 64 + qn + ni * 16 + l15;
                float val = acc[mi][ni][r];
                if (MODE == 0) {
                    if (bn < 3)
                        obf[(long)row * CC + col] = (__bf16)((val + b0[col]) * QSCALE_L2E);
                    else
                        obf2[(long)row * CC + (col - 192)] = (__bf16)(val + b1[col - 192]);
                } else if (MODE == 1) {
                    obf[(long)row * 384 + col] = (__bf16)(val + b0[col]);
                } else {
                    int win = row >> 8, q = row & 255;
                    int bb = win / 100, wr = win % 100, wy = wr / 10, wx = wr % 10;
                    int y = wy * 16 + (q >> 4), xx = wx * 16 + (q & 15);
                    of[((long)((bb * CH + y) * CW + xx)) * CC + col] = val + b0[col];
                }
            }
        }
    }
}

// ---------------------------------------------------------------------------
// Attention v3: swapped-operand 32x32 MFMA, in-register softmax, NO cross-lane
// P movement. S^T = mfma(K, Q): lane owns column q = lane&31. The PV MFMA's
// slot->kv assignment is CHOSEN to equal the C-layout order of st[] (slot e at
// lane-group hi holds kv = 4*hi + (e&3) + 8*(e>>2)), so P packs are lane-local
// and V fragments are loaded from LDS at exactly those kv columns. Max/sum
// cross-half exchange uses __shfl_xor(x,32) (guaranteed semantics).
// ---------------------------------------------------------------------------
__global__ __launch_bounds__(256)
void attn3_k(const __bf16* __restrict__ Q, const __bf16* __restrict__ KV,
             const __bf16* __restrict__ G, const __bf16* __restrict__ BT,
             __bf16* __restrict__ Y)
{
    __shared__ __bf16 Ks[2][64][44];   // [buf][kv][d]  row 88B (2-way conflict max)
    __shared__ __bf16 Vt[2][32][76];   // [buf][d][kv]  row 152B (2-way conflict max)

    const int head = blockIdx.x, win = blockIdx.y;
    const int bb = win / 100, wr = win % 100, wy = wr / 10, wx = wr % 10;
    const int cy = (wy == 0) ? 0 : ((wy == 9) ? 2 : 1);
    const int cx = (wx == 0) ? 0 : ((wx == 9) ? 2 : 1);
    const int cls = cy * 3 + cx;
    const int t = threadIdx.x, lane = t & 63, wv = t >> 6;
    const int l31 = lane & 31, hi = lane >> 5;

    // Q fragments: Q[q=l31][d = dk*16 + hi*8 + j], pre-scaled by scale*log2e
    bf16x8 qf[2][2];
    const __bf16* qb = Q + ((long)win * CNQ + wv * 64) * CC + head * CD;
#pragma unroll
    for (int qt = 0; qt < 2; ++qt)
#pragma unroll
        for (int dk = 0; dk < 2; ++dk)
            qf[qt][dk] = *(const bf16x8*)(qb + (qt * 32 + l31) * CC + dk * 16 + hi * 8);

    f32x16 o[2] = {};
    float mrun[2] = {-1e30f, -1e30f};
    float srun[2] = {0.f, 0.f};

    const int srow = t >> 2, sseg = t & 3;

    // --- prologue: stage chunk 0 ---
    {
        int oy = srow / 24, ox = srow - oy * 24;
        const __bf16* p = KV + ((long)((bb * CPH + wy * 16 + oy) * CPH + wx * 16 + ox)) * 384
                          + head * CD + sseg * 8;
        bf16x8 kr = *(const bf16x8*)p;
        bf16x8 vr = *(const bf16x8*)(p + CC);
        *(bf16x8*)&Ks[0][srow][sseg * 8] = kr;
#pragma unroll
        for (int j = 0; j < 8; ++j) Vt[0][sseg * 8 + j][srow] = vr[j];
    }
    __syncthreads();

    const __bf16* btbase = BT + ((long)cls * 55296 + (long)((head * 8 + wv * 2) * 18) * 64) * 16;

    for (int ch = 0; ch < 9; ++ch) {
        const int cur = ch & 1;
        bf16x8 kr, vr;
        if (ch < 8) {   // T14: issue next-chunk loads early
            int kvp = (ch + 1) * 64 + srow;
            int oy = kvp / 24, ox = kvp - oy * 24;
            const __bf16* p = KV + ((long)((bb * CPH + wy * 16 + oy) * CPH + wx * 16 + ox)) * 384
                              + head * CD + sseg * 8;
            kr = *(const bf16x8*)p;
            vr = *(const bf16x8*)(p + CC);
        }

#pragma unroll
        for (int kt = 0; kt < 2; ++kt) {
            const int ktg = ch * 2 + kt;
            bf16x8 kf0 = *(const bf16x8*)&Ks[cur][kt * 32 + l31][hi * 8];
            bf16x8 kf1 = *(const bf16x8*)&Ks[cur][kt * 32 + l31][16 + hi * 8];
            // V fragments in the chosen slot->kv order: slot e <-> kv
            // = base + 4*hi + (e&3) + 8*(e>>2)
            bf16x4 v00 = *(const bf16x4*)&Vt[cur][l31][kt * 32 + 4 * hi];
            bf16x4 v01 = *(const bf16x4*)&Vt[cur][l31][kt * 32 + 8 + 4 * hi];
            bf16x4 v10 = *(const bf16x4*)&Vt[cur][l31][kt * 32 + 16 + 4 * hi];
            bf16x4 v11 = *(const bf16x4*)&Vt[cur][l31][kt * 32 + 24 + 4 * hi];
            bf16x8 vf0, vf1;
#pragma unroll
            for (int j = 0; j < 4; ++j) {
                vf0[j] = v00[j]; vf0[4 + j] = v01[j];
                vf1[j] = v10[j]; vf1[4 + j] = v11[j];
            }
#pragma unroll
            for (int qt = 0; qt < 2; ++qt) {
                // bias(+mask) as MFMA C-input
                const __bf16* bp = btbase + ((long)qt * 18 + ktg) * 1024 + lane * 16;
                bf16x8 b0 = *(const bf16x8*)bp;
                bf16x8 b1 = *(const bf16x8*)(bp + 8);
                f32x16 st;
#pragma unroll
                for (int r = 0; r < 8; ++r) st[r] = (float)b0[r];
#pragma unroll
                for (int r = 0; r < 8; ++r) st[8 + r] = (float)b1[r];
                st = MFMA32(kf0, qf[qt][0], st);
                st = MFMA32(kf1, qf[qt][1], st);

                // --- online softmax over this 32-kv tile (column q = l31) ---
                float cm = st[0];
#pragma unroll
                for (int r = 1; r < 16; ++r) cm = fmaxf(cm, st[r]);
                cm = fmaxf(cm, __shfl_xor(cm, 32));
                float mnew = fmaxf(mrun[qt], cm);
                float fac = exp2f(mrun[qt] - mnew);
                mrun[qt] = mnew;
                float ps = 0.f;
#pragma unroll
                for (int r = 0; r < 16; ++r) {
                    float p = exp2f(st[r] - mnew);
                    st[r] = p;
                    ps += p;
                }
                ps += __shfl_xor(ps, 32);
                srun[qt] = srun[qt] * fac + ps;
#pragma unroll
                for (int r = 0; r < 16; ++r) o[qt][r] *= fac;

                // --- pack P (lane-local; slot e <-> st[e] by construction) ---
                u32 w0 = pack_bf16(st[0], st[1]),   w1 = pack_bf16(st[2], st[3]);
                u32 w2 = pack_bf16(st[4], st[5]),   w3 = pack_bf16(st[6], st[7]);
                u32 w4 = pack_bf16(st[8], st[9]),   w5 = pack_bf16(st[10], st[11]);
                u32 w6 = pack_bf16(st[12], st[13]), w7 = pack_bf16(st[14], st[15]);
                u32 pw0[4] = {w0, w1, w2, w3};
                u32 pw1[4] = {w4, w5, w6, w7};
                bf16x8 pa0 = __builtin_bit_cast(bf16x8, *(ulonglong2*)pw0);
                bf16x8 pa1 = __builtin_bit_cast(bf16x8, *(ulonglong2*)pw1);

                // --- PV: O^T += V^T * P^T (slot-consistent A/B) ---
                o[qt] = MFMA32(vf0, pa0, o[qt]);
                o[qt] = MFMA32(vf1, pa1, o[qt]);
            }
        }

        if (ch < 8) {   // write-late half of T14 staging
            *(bf16x8*)&Ks[cur ^ 1][srow][sseg * 8] = kr;
#pragma unroll
            for (int j = 0; j < 8; ++j) Vt[cur ^ 1][sseg * 8 + j][srow] = vr[j];
        }
        __syncthreads();
    }

    // --- epilogue: normalize, gate (single f32 round), store bf16 ---
#pragma unroll
    for (int qt = 0; qt < 2; ++qt) {
        float rs = 1.0f / srun[qt];
        long base = ((long)win * CNQ + wv * 64 + qt * 32 + l31) * CC + head * CD;
#pragma unroll
        for (int r = 0; r < 16; ++r) {
            int d = (r & 3) + 8 * (r >> 2) + 4 * hi;
            float val = o[qt][r] * rs * (float)G[base + d];
            Y[base + d] = (__bf16)val;
        }
    }
}

// ---------------------------------------------------------------------------
extern "C" void kernel_launch(void* const* d_in, const int* in_sizes, int n_in,
                              void* d_out, int out_size, void* d_ws, size_t ws_size,
                              hipStream_t stream)
{
    (void)in_sizes; (void)n_in; (void)out_size; (void)ws_size;
    const float* x    = (const float*)d_in[0];
    const int*   rpi  = (const int*)  d_in[1];
    // d_in[2] = attn_mask (recomputed analytically via window classes)
    const float* q_w  = (const float*)d_in[3];
    const float* q_b  = (const float*)d_in[4];
    const float* kv_w = (const float*)d_in[5];
    const float* kv_b = (const float*)d_in[6];
    const float* btab = (const float*)d_in[7];
    const float* g_w  = (const float*)d_in[8];
    const float* g_b  = (const float*)d_in[9];
    const float* p_w  = (const float*)d_in[10];
    const float* p_b  = (const float*)d_in[11];
    float* out = (float*)d_out;

    char* ws = (char*)d_ws;
    __bf16* Qb  = (__bf16*)(ws);                  // 200*256*192*2      = 19,660,800 B
    __bf16* KVb = (__bf16*)(ws + 19660800);       // 2*168*168*384*2    = 43,352,064 B
    __bf16* Gb  = (__bf16*)(ws + 63012864);       // 200*256*192*2      = 19,660,800 B
    __bf16* Yb  = (__bf16*)(ws + 82673664);       // 200*256*192*2      = 19,660,800 B
    __bf16* BT  = (__bf16*)(ws + 102334464);      // 9*55296*16*2       = 15,925,248 B
                                                  // total 118,259,712 B

    bias2_k<<<216, 256, 0, stream>>>(rpi, btab, BT);
    gemm_k<0><<<dim3(800, 6), 256, 0, stream>>>(x, nullptr, q_w, g_w, q_b, g_b,
                                                Qb, Gb, nullptr);
    gemm_k<1><<<dim3(882, 6), 256, 0, stream>>>(x, nullptr, kv_w, nullptr, kv_b, nullptr,
                                                KVb, nullptr, nullptr);
    attn3_k<<<dim3(6, 200), 256, 0, stream>>>(Qb, KVb, Gb, BT, Yb);
    gemm_k<2><<<dim3(800, 3), 256, 0, stream>>>(nullptr, Yb, p_w, nullptr, p_b, nullptr,
                                                nullptr, nullptr, out);
}

// Round 4
// 239.965 us; speedup vs baseline: 1.7824x; 1.0797x over previous
//
#include <hip/hip_runtime.h>
#include <hip/hip_bf16.h>
#include <stdint.h>

typedef __bf16 bf16x8 __attribute__((ext_vector_type(8)));
typedef __bf16 bf16x4 __attribute__((ext_vector_type(4)));
typedef float  f32x4  __attribute__((ext_vector_type(4)));
typedef float  f32x16 __attribute__((ext_vector_type(16)));
typedef uint32_t u32;

#define MFMA16(a, b, c) __builtin_amdgcn_mfma_f32_16x16x32_bf16((a), (b), (c), 0, 0, 0)
#define MFMA32(a, b, c) __builtin_amdgcn_mfma_f32_32x32x16_bf16((a), (b), (c), 0, 0, 0)

constexpr int CH = 160, CW = 160, CC = 192, CHEADS = 6, CD = 32;
constexpr int CPAD = 4;
constexpr int CNQ = 256, CNKV = 576, CPH = 168;
constexpr float LOG2E = 1.44269504088896340736f;
constexpr float QSCALE_L2E = 0.17677669529663687f * 1.44269504088896340736f;

static __device__ __forceinline__ u32 pack_bf16(float lo, float hi) {
    __bf16 a = (__bf16)lo, b = (__bf16)hi;
    u32 ua = (u32)__builtin_bit_cast(unsigned short, a);
    u32 ub = (u32)__builtin_bit_cast(unsigned short, b);
    return ua | (ub << 16);
}

// ---------------------------------------------------------------------------
// f32 bias table, UNREPLICATED (L2-resident, 3.54 MB):
// btf[((head*8 + qtg)*18 + ktg)*64 + lane][16],
// value = bias_table[rpi[q][kv]][head] * log2e, with
// q = qtg*32 + (lane&31), kv = ktg*32 + 4*(lane>>5) + (r&3) + 8*(r>>2).
// ---------------------------------------------------------------------------
__global__ __launch_bounds__(256)
void biasf_k(const int* __restrict__ rpi, const float* __restrict__ tab,
             float* __restrict__ btf)
{
    int idx = blockIdx.x * 256 + threadIdx.x;  // 6*8*18*64 = 55296
    int lane = idx & 63;
    int rest = idx >> 6;
    int ktg = rest % 18; rest /= 18;
    int qtg = rest & 7;
    int head = rest >> 3;
    int l31 = lane & 31, hi = lane >> 5;
    int q = qtg * 32 + l31;

    float bv[16];
#pragma unroll
    for (int g = 0; g < 4; ++g) {
        int4 ri = *(const int4*)(rpi + q * CNKV + ktg * 32 + 4 * hi + g * 8);
        bv[g * 4 + 0] = tab[ri.x * CHEADS + head] * LOG2E;
        bv[g * 4 + 1] = tab[ri.y * CHEADS + head] * LOG2E;
        bv[g * 4 + 2] = tab[ri.z * CHEADS + head] * LOG2E;
        bv[g * 4 + 3] = tab[ri.w * CHEADS + head] * LOG2E;
    }
    float* dst = btf + (long)idx * 16;
#pragma unroll
    for (int g = 0; g < 4; ++g)
        *(float4*)(dst + g * 4) = *(float4*)&bv[g * 4];
}

// ---------------------------------------------------------------------------
// Validity bitmask table MT[cls 9][ktg 18][lane 64] (41 KB):
// bit r set iff kv(ktg, lane, r) is a valid (non-padded) position for cls.
// ---------------------------------------------------------------------------
__global__ __launch_bounds__(256)
void mask_k(u32* __restrict__ mt)
{
    int idx = blockIdx.x * 256 + threadIdx.x;  // 9*18*64 = 10368
    if (idx >= 9 * 18 * 64) return;
    int lane = idx & 63;
    int rest = idx >> 6;
    int ktg = rest % 18;
    int cls = rest / 18;
    int cy = cls / 3, cx = cls % 3;
    int hi = lane >> 5;
    u32 m = 0;
#pragma unroll
    for (int r = 0; r < 16; ++r) {
        int kv = ktg * 32 + 4 * hi + (r & 3) + 8 * (r >> 2);
        int oy = kv / 24, ox = kv - oy * 24;
        bool vy = (cy == 0) ? (oy >= 4) : ((cy == 2) ? (oy < 20) : true);
        bool vx = (cx == 0) ? (ox >= 4) : ((cx == 2) ? (ox < 20) : true);
        if (vy && vx) m |= (1u << r);
    }
    mt[idx] = m;
}

// ---------------------------------------------------------------------------
// Generic MFMA GEMM (unchanged from R3). MODE 0: x -> Q(bf16) + Gates(bf16)
//   MODE 1: x_pad -> KV(bf16)   MODE 2: Y(bf16, window) -> out(fp32, image)
// ---------------------------------------------------------------------------
template <int MODE>
__global__ __launch_bounds__(256)
void gemm_k(const float* __restrict__ xin, const __bf16* __restrict__ yin,
            const float* __restrict__ w0, const float* __restrict__ w1,
            const float* __restrict__ b0, const float* __restrict__ b1,
            __bf16* __restrict__ obf, __bf16* __restrict__ obf2,
            float* __restrict__ of)
{
    __shared__ __bf16 As[64][40];
    __shared__ __bf16 Bt[64][40];

    const int t = threadIdx.x;
    const int lane = t & 63, wv = t >> 6;
    const int bm = blockIdx.x, bn = blockIdx.y;
    const int l15 = lane & 15, l4 = lane >> 4;

    const int arow = t >> 2, aseg = t & 3;
    const int m_st = bm * 64 + arow;
    long aoff = 0;
    bool avalid = true;
    if (MODE == 0) {
        int win = m_st >> 8, q = m_st & 255;
        int bb = win / 100, wr = win % 100, wy = wr / 10, wx = wr % 10;
        int y = wy * 16 + (q >> 4), xx = wx * 16 + (q & 15);
        aoff = ((long)((bb * CH + y) * CW + xx)) * CC;
    } else if (MODE == 1) {
        int bb = m_st / (CPH * CPH), r = m_st % (CPH * CPH);
        int py = r / CPH, px = r % CPH;
        int y = py - CPAD, xx = px - CPAD;
        avalid = ((unsigned)y < (unsigned)CH) && ((unsigned)xx < (unsigned)CW);
        aoff = avalid ? ((long)((bb * CH + y) * CW + xx)) * CC : 0;
    } else {
        aoff = (long)m_st * CC;
    }

    const int bkr = t >> 3, bcs = t & 7;
    const float* wsrc; int ldw, cbase;
    if (MODE == 0) {
        if (bn < 3) { wsrc = w0; ldw = 192; cbase = bn * 64; }
        else        { wsrc = w1; ldw = 192; cbase = (bn - 3) * 64; }
    } else if (MODE == 1) { wsrc = w0; ldw = 384; cbase = bn * 64; }
    else                  { wsrc = w0; ldw = 192; cbase = bn * 64; }

    const int qm = (wv >> 1) * 32, qn = (wv & 1) * 32;
    f32x4 acc[2][2];
#pragma unroll
    for (int i = 0; i < 2; ++i)
#pragma unroll
        for (int j = 0; j < 2; ++j) acc[i][j] = f32x4{0.f, 0.f, 0.f, 0.f};

    for (int kt = 0; kt < 6; ++kt) {
        const int k0 = kt * 32;
        __syncthreads();
        if (MODE == 2) {
            bf16x8 v = *(const bf16x8*)(yin + aoff + k0 + aseg * 8);
            *(bf16x8*)&As[arow][aseg * 8] = v;
        } else {
            __bf16* d = &As[arow][aseg * 8];
            if (avalid) {
                const float* src = xin + aoff + k0 + aseg * 8;
                float4 v0 = *(const float4*)(src);
                float4 v1 = *(const float4*)(src + 4);
                d[0] = (__bf16)v0.x; d[1] = (__bf16)v0.y;
                d[2] = (__bf16)v0.z; d[3] = (__bf16)v0.w;
                d[4] = (__bf16)v1.x; d[5] = (__bf16)v1.y;
                d[6] = (__bf16)v1.z; d[7] = (__bf16)v1.w;
            } else {
#pragma unroll
                for (int j = 0; j < 8; ++j) d[j] = (__bf16)0.f;
            }
        }
        {
            const float* src = wsrc + (long)(k0 + bkr) * ldw + cbase + bcs * 8;
            float4 u0 = *(const float4*)(src);
            float4 u1 = *(const float4*)(src + 4);
            Bt[bcs * 8 + 0][bkr] = (__bf16)u0.x; Bt[bcs * 8 + 1][bkr] = (__bf16)u0.y;
            Bt[bcs * 8 + 2][bkr] = (__bf16)u0.z; Bt[bcs * 8 + 3][bkr] = (__bf16)u0.w;
            Bt[bcs * 8 + 4][bkr] = (__bf16)u1.x; Bt[bcs * 8 + 5][bkr] = (__bf16)u1.y;
            Bt[bcs * 8 + 6][bkr] = (__bf16)u1.z; Bt[bcs * 8 + 7][bkr] = (__bf16)u1.w;
        }
        __syncthreads();
        bf16x8 af[2], bfr[2];
#pragma unroll
        for (int mi = 0; mi < 2; ++mi)
            af[mi] = *(const bf16x8*)&As[qm + mi * 16 + l15][l4 * 8];
#pragma unroll
        for (int ni = 0; ni < 2; ++ni)
            bfr[ni] = *(const bf16x8*)&Bt[qn + ni * 16 + l15][l4 * 8];
#pragma unroll
        for (int mi = 0; mi < 2; ++mi)
#pragma unroll
            for (int ni = 0; ni < 2; ++ni)
                acc[mi][ni] = MFMA16(af[mi], bfr[ni], acc[mi][ni]);
    }

#pragma unroll
    for (int mi = 0; mi < 2; ++mi) {
#pragma unroll
        for (int ni = 0; ni < 2; ++ni) {
#pragma unroll
            for (int r = 0; r < 4; ++r) {
                int row = bm * 64 + qm + mi * 16 + l4 * 4 + r;
                int col = bn * 64 + qn + ni * 16 + l15;
                float val = acc[mi][ni][r];
                if (MODE == 0) {
                    if (bn < 3)
                        obf[(long)row * CC + col] = (__bf16)((val + b0[col]) * QSCALE_L2E);
                    else
                        obf2[(long)row * CC + (col - 192)] = (__bf16)(val + b1[col - 192]);
                } else if (MODE == 1) {
                    obf[(long)row * 384 + col] = (__bf16)(val + b0[col]);
                } else {
                    int win = row >> 8, q = row & 255;
                    int bb = win / 100, wr = win % 100, wy = wr / 10, wx = wr % 10;
                    int y = wy * 16 + (q >> 4), xx = wx * 16 + (q & 15);
                    of[((long)((bb * CH + y) * CW + xx)) * CC + col] = val + b0[col];
                }
            }
        }
    }
}

// ---------------------------------------------------------------------------
// Attention v4: no-max softmax (exp2 of raw score; exact softmax by shift
// invariance — scores are O(1) here, overflow needs |st|>120), unreplicated
// f32 bias as MFMA C-input, analytic border masking, XCD-swizzled grid.
// ---------------------------------------------------------------------------
__global__ __launch_bounds__(256)
void attn4_k(const __bf16* __restrict__ Q, const __bf16* __restrict__ KV,
             const __bf16* __restrict__ G, const float* __restrict__ BTf,
             const u32* __restrict__ MT, __bf16* __restrict__ Y)
{
    __shared__ __bf16 Ks[2][64][44];   // [buf][kv][d]
    __shared__ __bf16 Vt[2][32][76];   // [buf][d][kv]

    // XCD swizzle: all 6 heads of a window on one XCD (KV L2 reuse).
    const int bid = blockIdx.x;            // 1200 = 8 * 150
    const int xs = bid & 7, ii = bid >> 3;
    const int win = xs * 25 + ii / 6;
    const int head = ii % 6;

    const int bb = win / 100, wr = win % 100, wy = wr / 10, wx = wr % 10;
    const int cy = (wy == 0) ? 0 : ((wy == 9) ? 2 : 1);
    const int cx = (wx == 0) ? 0 : ((wx == 9) ? 2 : 1);
    const int cls = cy * 3 + cx;
    const int t = threadIdx.x, lane = t & 63, wv = t >> 6;
    const int l31 = lane & 31, hi = lane >> 5;

    bf16x8 qf[2][2];
    const __bf16* qb = Q + ((long)win * CNQ + wv * 64) * CC + head * CD;
#pragma unroll
    for (int qt = 0; qt < 2; ++qt)
#pragma unroll
        for (int dk = 0; dk < 2; ++dk)
            qf[qt][dk] = *(const bf16x8*)(qb + (qt * 32 + l31) * CC + dk * 16 + hi * 8);

    f32x16 o[2] = {};
    float srun[2] = {0.f, 0.f};

    const int srow = t >> 2, sseg = t & 3;

    // --- prologue: stage chunk 0 ---
    {
        int oy = srow / 24, ox = srow - oy * 24;
        const __bf16* p = KV + ((long)((bb * CPH + wy * 16 + oy) * CPH + wx * 16 + ox)) * 384
                          + head * CD + sseg * 8;
        bf16x8 kr = *(const bf16x8*)p;
        bf16x8 vr = *(const bf16x8*)(p + CC);
        *(bf16x8*)&Ks[0][srow][sseg * 8] = kr;
#pragma unroll
        for (int j = 0; j < 8; ++j) Vt[0][sseg * 8 + j][srow] = vr[j];
    }
    __syncthreads();

    const float* btb = BTf + ((long)((head * 8 + wv * 2) * 18) * 64) * 16;

    for (int ch = 0; ch < 9; ++ch) {
        const int cur = ch & 1;
        bf16x8 kr, vr;
        if (ch < 8) {   // T14: issue next-chunk loads early
            int kvp = (ch + 1) * 64 + srow;
            int oy = kvp / 24, ox = kvp - oy * 24;
            const __bf16* p = KV + ((long)((bb * CPH + wy * 16 + oy) * CPH + wx * 16 + ox)) * 384
                              + head * CD + sseg * 8;
            kr = *(const bf16x8*)p;
            vr = *(const bf16x8*)(p + CC);
        }

#pragma unroll
        for (int kt = 0; kt < 2; ++kt) {
            const int ktg = ch * 2 + kt;
            bf16x8 kf0 = *(const bf16x8*)&Ks[cur][kt * 32 + l31][hi * 8];
            bf16x8 kf1 = *(const bf16x8*)&Ks[cur][kt * 32 + l31][16 + hi * 8];
            bf16x4 v00 = *(const bf16x4*)&Vt[cur][l31][kt * 32 + 4 * hi];
            bf16x4 v01 = *(const bf16x4*)&Vt[cur][l31][kt * 32 + 8 + 4 * hi];
            bf16x4 v10 = *(const bf16x4*)&Vt[cur][l31][kt * 32 + 16 + 4 * hi];
            bf16x4 v11 = *(const bf16x4*)&Vt[cur][l31][kt * 32 + 24 + 4 * hi];
            bf16x8 vf0, vf1;
#pragma unroll
            for (int j = 0; j < 4; ++j) {
                vf0[j] = v00[j]; vf0[4 + j] = v01[j];
                vf1[j] = v10[j]; vf1[4 + j] = v11[j];
            }

            // block-uniform: does this 32-kv tile contain padded positions?
            const bool needm = (cx != 1) || (cy == 0 && ktg < 3) || (cy == 2 && ktg >= 15);
            u32 m = 0xFFFFFFFFu;
            if (needm) m = MT[(cls * 18 + ktg) * 64 + lane];

#pragma unroll
            for (int qt = 0; qt < 2; ++qt) {
                const float* bp = btb + ((long)qt * 18 + ktg) * 1024 + lane * 16;
                float4 c0 = *(const float4*)(bp);
                float4 c1 = *(const float4*)(bp + 4);
                float4 c2 = *(const float4*)(bp + 8);
                float4 c3 = *(const float4*)(bp + 12);
                f32x16 st = {c0.x, c0.y, c0.z, c0.w, c1.x, c1.y, c1.z, c1.w,
                             c2.x, c2.y, c2.z, c2.w, c3.x, c3.y, c3.z, c3.w};
                __builtin_amdgcn_s_setprio(1);
                st = MFMA32(kf0, qf[qt][0], st);
                st = MFMA32(kf1, qf[qt][1], st);
                __builtin_amdgcn_s_setprio(0);

                float p[16];
#pragma unroll
                for (int r = 0; r < 16; ++r) p[r] = exp2f(st[r]);
                if (needm) {
#pragma unroll
                    for (int r = 0; r < 16; ++r)
                        p[r] = (m & (1u << r)) ? p[r] : 0.0f;
                }
                float s = srun[qt];
#pragma unroll
                for (int r = 0; r < 16; ++r) s += p[r];
                srun[qt] = s;

                u32 w0 = pack_bf16(p[0], p[1]),   w1 = pack_bf16(p[2], p[3]);
                u32 w2 = pack_bf16(p[4], p[5]),   w3 = pack_bf16(p[6], p[7]);
                u32 w4 = pack_bf16(p[8], p[9]),   w5 = pack_bf16(p[10], p[11]);
                u32 w6 = pack_bf16(p[12], p[13]), w7 = pack_bf16(p[14], p[15]);
                u32 pw0[4] = {w0, w1, w2, w3};
                u32 pw1[4] = {w4, w5, w6, w7};
                bf16x8 pa0 = __builtin_bit_cast(bf16x8, *(ulonglong2*)pw0);
                bf16x8 pa1 = __builtin_bit_cast(bf16x8, *(ulonglong2*)pw1);

                __builtin_amdgcn_s_setprio(1);
                o[qt] = MFMA32(vf0, pa0, o[qt]);
                o[qt] = MFMA32(vf1, pa1, o[qt]);
                __builtin_amdgcn_s_setprio(0);
            }
        }

        if (ch < 8) {   // write-late half of T14 staging
            *(bf16x8*)&Ks[cur ^ 1][srow][sseg * 8] = kr;
#pragma unroll
            for (int j = 0; j < 8; ++j) Vt[cur ^ 1][sseg * 8 + j][srow] = vr[j];
        }
        __syncthreads();
    }

    // --- epilogue: cross-half sum (deferred), normalize, gate, store ---
#pragma unroll
    for (int qt = 0; qt < 2; ++qt) {
        float sq = srun[qt] + __shfl_xor(srun[qt], 32);
        float rs = 1.0f / sq;
        long base = ((long)win * CNQ + wv * 64 + qt * 32 + l31) * CC + head * CD;
#pragma unroll
        for (int r = 0; r < 16; ++r) {
            int d = (r & 3) + 8 * (r >> 2) + 4 * hi;
            float val = o[qt][r] * rs * (float)G[base + d];
            Y[base + d] = (__bf16)val;
        }
    }
}

// ---------------------------------------------------------------------------
extern "C" void kernel_launch(void* const* d_in, const int* in_sizes, int n_in,
                              void* d_out, int out_size, void* d_ws, size_t ws_size,
                              hipStream_t stream)
{
    (void)in_sizes; (void)n_in; (void)out_size; (void)ws_size;
    const float* x    = (const float*)d_in[0];
    const int*   rpi  = (const int*)  d_in[1];
    // d_in[2] = attn_mask (recomputed analytically)
    const float* q_w  = (const float*)d_in[3];
    const float* q_b  = (const float*)d_in[4];
    const float* kv_w = (const float*)d_in[5];
    const float* kv_b = (const float*)d_in[6];
    const float* btab = (const float*)d_in[7];
    const float* g_w  = (const float*)d_in[8];
    const float* g_b  = (const float*)d_in[9];
    const float* p_w  = (const float*)d_in[10];
    const float* p_b  = (const float*)d_in[11];
    float* out = (float*)d_out;

    char* ws = (char*)d_ws;
    __bf16* Qb  = (__bf16*)(ws);                  // 19,660,800 B
    __bf16* KVb = (__bf16*)(ws + 19660800);       // 43,352,064 B
    __bf16* Gb  = (__bf16*)(ws + 63012864);       // 19,660,800 B
    __bf16* Yb  = (__bf16*)(ws + 82673664);       // 19,660,800 B
    float*  BTf = (float*)(ws + 102334464);       // 55296*16*4 = 3,538,944 B
    u32*    MT  = (u32*)(ws + 105873408);         // 10368*4    = 41,472 B
                                                  // total 105,914,880 B

    biasf_k<<<216, 256, 0, stream>>>(rpi, btab, BTf);
    mask_k<<<41, 256, 0, stream>>>(MT);
    gemm_k<0><<<dim3(800, 6), 256, 0, stream>>>(x, nullptr, q_w, g_w, q_b, g_b,
                                                Qb, Gb, nullptr);
    gemm_k<1><<<dim3(882, 6), 256, 0, stream>>>(x, nullptr, kv_w, nullptr, kv_b, nullptr,
                                                KVb, nullptr, nullptr);
    attn4_k<<<1200, 256, 0, stream>>>(Qb, KVb, Gb, BTf, MT, Yb);
    gemm_k<2><<<dim3(800, 3), 256, 0, stream>>>(nullptr, Yb, p_w, nullptr, p_b, nullptr,
                                                nullptr, nullptr, out);
}

// Round 5
// 224.593 us; speedup vs baseline: 1.9044x; 1.0684x over previous
//
#include <hip/hip_runtime.h>
#include <hip/hip_bf16.h>
#include <stdint.h>

typedef __bf16 bf16x8 __attribute__((ext_vector_type(8)));
typedef __bf16 bf16x4 __attribute__((ext_vector_type(4)));
typedef float  f32x4  __attribute__((ext_vector_type(4)));
typedef float  f32x16 __attribute__((ext_vector_type(16)));
typedef uint32_t u32;

#define MFMA16(a, b, c) __builtin_amdgcn_mfma_f32_16x16x32_bf16((a), (b), (c), 0, 0, 0)
#define MFMA32(a, b, c) __builtin_amdgcn_mfma_f32_32x32x16_bf16((a), (b), (c), 0, 0, 0)

constexpr int CH = 160, CW = 160, CC = 192, CHEADS = 6, CD = 32;
constexpr int CPAD = 4;
constexpr int CNQ = 256, CNKV = 576, CPH = 168;
constexpr float LOG2E = 1.44269504088896340736f;
constexpr float QSCALE_L2E = 0.17677669529663687f * 1.44269504088896340736f;

static __device__ __forceinline__ u32 pack_bf16(float lo, float hi) {
    __bf16 a = (__bf16)lo, b = (__bf16)hi;
    u32 ua = (u32)__builtin_bit_cast(unsigned short, a);
    u32 ub = (u32)__builtin_bit_cast(unsigned short, b);
    return ua | (ub << 16);
}

struct BiasT { float4 a, b, c, d; };
static __device__ __forceinline__ BiasT load_bias(const float* p) {
    BiasT r;
    r.a = *(const float4*)(p);
    r.b = *(const float4*)(p + 4);
    r.c = *(const float4*)(p + 8);
    r.d = *(const float4*)(p + 12);
    return r;
}
static __device__ __forceinline__ f32x16 b2v(const BiasT& b) {
    return f32x16{b.a.x, b.a.y, b.a.z, b.a.w, b.b.x, b.b.y, b.b.z, b.b.w,
                  b.c.x, b.c.y, b.c.z, b.c.w, b.d.x, b.d.y, b.d.z, b.d.w};
}

// ---------------------------------------------------------------------------
// f32 bias table, UNREPLICATED (L2-resident, 3.54 MB):
// btf[((head*8 + qtg)*18 + ktg)*64 + lane][16]
// ---------------------------------------------------------------------------
__global__ __launch_bounds__(256)
void biasf_k(const int* __restrict__ rpi, const float* __restrict__ tab,
             float* __restrict__ btf)
{
    int idx = blockIdx.x * 256 + threadIdx.x;  // 6*8*18*64 = 55296
    int lane = idx & 63;
    int rest = idx >> 6;
    int ktg = rest % 18; rest /= 18;
    int qtg = rest & 7;
    int head = rest >> 3;
    int l31 = lane & 31, hi = lane >> 5;
    int q = qtg * 32 + l31;

    float bv[16];
#pragma unroll
    for (int g = 0; g < 4; ++g) {
        int4 ri = *(const int4*)(rpi + q * CNKV + ktg * 32 + 4 * hi + g * 8);
        bv[g * 4 + 0] = tab[ri.x * CHEADS + head] * LOG2E;
        bv[g * 4 + 1] = tab[ri.y * CHEADS + head] * LOG2E;
        bv[g * 4 + 2] = tab[ri.z * CHEADS + head] * LOG2E;
        bv[g * 4 + 3] = tab[ri.w * CHEADS + head] * LOG2E;
    }
    float* dst = btf + (long)idx * 16;
#pragma unroll
    for (int g = 0; g < 4; ++g)
        *(float4*)(dst + g * 4) = *(float4*)&bv[g * 4];
}

// ---------------------------------------------------------------------------
// Validity bitmask table MT[cls 9][ktg 18][lane 64] (41 KB)
// ---------------------------------------------------------------------------
__global__ __launch_bounds__(256)
void mask_k(u32* __restrict__ mt)
{
    int idx = blockIdx.x * 256 + threadIdx.x;  // 9*18*64 = 10368
    if (idx >= 9 * 18 * 64) return;
    int lane = idx & 63;
    int rest = idx >> 6;
    int ktg = rest % 18;
    int cls = rest / 18;
    int cy = cls / 3, cx = cls % 3;
    int hi = lane >> 5;
    u32 m = 0;
#pragma unroll
    for (int r = 0; r < 16; ++r) {
        int kv = ktg * 32 + 4 * hi + (r & 3) + 8 * (r >> 2);
        int oy = kv / 24, ox = kv - oy * 24;
        bool vy = (cy == 0) ? (oy >= 4) : ((cy == 2) ? (oy < 20) : true);
        bool vx = (cx == 0) ? (ox >= 4) : ((cx == 2) ? (ox < 20) : true);
        if (vy && vx) m |= (1u << r);
    }
    mt[idx] = m;
}

// ---------------------------------------------------------------------------
// Generic MFMA GEMM, BK=64 (3 K-iters, 6 barriers).
// MODE 0: x -> Q(bf16) + Gates(bf16); MODE 1: x_pad -> KV(bf16);
// MODE 2: Y(bf16, window) -> out(fp32, image).
// ---------------------------------------------------------------------------
template <int MODE>
__global__ __launch_bounds__(256)
void gemm_k(const float* __restrict__ xin, const __bf16* __restrict__ yin,
            const float* __restrict__ w0, const float* __restrict__ w1,
            const float* __restrict__ b0, const float* __restrict__ b1,
            __bf16* __restrict__ obf, __bf16* __restrict__ obf2,
            float* __restrict__ of)
{
    __shared__ __bf16 As[64][72];   // 144-B rows, 16-B aligned
    __shared__ __bf16 Bt[64][72];

    const int t = threadIdx.x;
    const int lane = t & 63, wv = t >> 6;
    const int bm = blockIdx.x, bn = blockIdx.y;
    const int l15 = lane & 15, l4 = lane >> 4;

    const int arow = t >> 2, aseg = t & 3;   // 16 elems per (row, seg)
    const int m_st = bm * 64 + arow;
    long aoff = 0;
    bool avalid = true;
    if (MODE == 0) {
        int win = m_st >> 8, q = m_st & 255;
        int bb = win / 100, wr = win % 100, wy = wr / 10, wx = wr % 10;
        int y = wy * 16 + (q >> 4), xx = wx * 16 + (q & 15);
        aoff = ((long)((bb * CH + y) * CW + xx)) * CC;
    } else if (MODE == 1) {
        int bb = m_st / (CPH * CPH), r = m_st % (CPH * CPH);
        int py = r / CPH, px = r % CPH;
        int y = py - CPAD, xx = px - CPAD;
        avalid = ((unsigned)y < (unsigned)CH) && ((unsigned)xx < (unsigned)CW);
        aoff = avalid ? ((long)((bb * CH + y) * CW + xx)) * CC : 0;
    } else {
        aoff = (long)m_st * CC;
    }

    const float* wsrc; int ldw, cbase;
    if (MODE == 0) {
        if (bn < 3) { wsrc = w0; ldw = 192; cbase = bn * 64; }
        else        { wsrc = w1; ldw = 192; cbase = (bn - 3) * 64; }
    } else if (MODE == 1) { wsrc = w0; ldw = 384; cbase = bn * 64; }
    else                  { wsrc = w0; ldw = 192; cbase = bn * 64; }

    const int qm = (wv >> 1) * 32, qn = (wv & 1) * 32;
    f32x4 acc[2][2];
#pragma unroll
    for (int i = 0; i < 2; ++i)
#pragma unroll
        for (int j = 0; j < 2; ++j) acc[i][j] = f32x4{0.f, 0.f, 0.f, 0.f};

    for (int kt = 0; kt < 3; ++kt) {
        const int k0 = kt * 64;
        __syncthreads();
        // ---- A stage (16 elems/thread) ----
        if (MODE == 2) {
            bf16x8 v0 = *(const bf16x8*)(yin + aoff + k0 + aseg * 16);
            bf16x8 v1 = *(const bf16x8*)(yin + aoff + k0 + aseg * 16 + 8);
            *(bf16x8*)&As[arow][aseg * 16] = v0;
            *(bf16x8*)&As[arow][aseg * 16 + 8] = v1;
        } else {
            __bf16* d = &As[arow][aseg * 16];
            if (avalid) {
                const float* src = xin + aoff + k0 + aseg * 16;
                float4 q0 = ((const float4*)src)[0];
                float4 q1 = ((const float4*)src)[1];
                float4 q2 = ((const float4*)src)[2];
                float4 q3 = ((const float4*)src)[3];
                d[0]  = (__bf16)q0.x; d[1]  = (__bf16)q0.y;
                d[2]  = (__bf16)q0.z; d[3]  = (__bf16)q0.w;
                d[4]  = (__bf16)q1.x; d[5]  = (__bf16)q1.y;
                d[6]  = (__bf16)q1.z; d[7]  = (__bf16)q1.w;
                d[8]  = (__bf16)q2.x; d[9]  = (__bf16)q2.y;
                d[10] = (__bf16)q2.z; d[11] = (__bf16)q2.w;
                d[12] = (__bf16)q3.x; d[13] = (__bf16)q3.y;
                d[14] = (__bf16)q3.z; d[15] = (__bf16)q3.w;
            } else {
#pragma unroll
                for (int j = 0; j < 16; ++j) d[j] = (__bf16)0.f;
            }
        }
        // ---- B stage (transpose, 16 elems/thread) ----
        {
            const float* src = wsrc + (long)(k0 + arow) * ldw + cbase + aseg * 16;
            float4 u0 = ((const float4*)src)[0];
            float4 u1 = ((const float4*)src)[1];
            float4 u2 = ((const float4*)src)[2];
            float4 u3 = ((const float4*)src)[3];
            const int cb = aseg * 16;
            Bt[cb + 0][arow]  = (__bf16)u0.x; Bt[cb + 1][arow]  = (__bf16)u0.y;
            Bt[cb + 2][arow]  = (__bf16)u0.z; Bt[cb + 3][arow]  = (__bf16)u0.w;
            Bt[cb + 4][arow]  = (__bf16)u1.x; Bt[cb + 5][arow]  = (__bf16)u1.y;
            Bt[cb + 6][arow]  = (__bf16)u1.z; Bt[cb + 7][arow]  = (__bf16)u1.w;
            Bt[cb + 8][arow]  = (__bf16)u2.x; Bt[cb + 9][arow]  = (__bf16)u2.y;
            Bt[cb + 10][arow] = (__bf16)u2.z; Bt[cb + 11][arow] = (__bf16)u2.w;
            Bt[cb + 12][arow] = (__bf16)u3.x; Bt[cb + 13][arow] = (__bf16)u3.y;
            Bt[cb + 14][arow] = (__bf16)u3.z; Bt[cb + 15][arow] = (__bf16)u3.w;
        }
        __syncthreads();
        // ---- MFMA: two K=32 sub-steps ----
#pragma unroll
        for (int s = 0; s < 2; ++s) {
            bf16x8 af[2], bfr[2];
#pragma unroll
            for (int mi = 0; mi < 2; ++mi)
                af[mi] = *(const bf16x8*)&As[qm + mi * 16 + l15][s * 32 + l4 * 8];
#pragma unroll
            for (int ni = 0; ni < 2; ++ni)
                bfr[ni] = *(const bf16x8*)&Bt[qn + ni * 16 + l15][s * 32 + l4 * 8];
#pragma unroll
            for (int mi = 0; mi < 2; ++mi)
#pragma unroll
                for (int ni = 0; ni < 2; ++ni)
                    acc[mi][ni] = MFMA16(af[mi], bfr[ni], acc[mi][ni]);
        }
    }

#pragma unroll
    for (int mi = 0; mi < 2; ++mi) {
#pragma unroll
        for (int ni = 0; ni < 2; ++ni) {
#pragma unroll
            for (int r = 0; r < 4; ++r) {
                int row = bm * 64 + qm + mi * 16 + l4 * 4 + r;
                int col = bn * 64 + qn + ni * 16 + l15;
                float val = acc[mi][ni][r];
                if (MODE == 0) {
                    if (bn < 3)
                        obf[(long)row * CC + col] = (__bf16)((val + b0[col]) * QSCALE_L2E);
                    else
                        obf2[(long)row * CC + (col - 192)] = (__bf16)(val + b1[col - 192]);
                } else if (MODE == 1) {
                    obf[(long)row * 384 + col] = (__bf16)(val + b0[col]);
                } else {
                    int win = row >> 8, q = row & 255;
                    int bb = win / 100, wr = win % 100, wy = wr / 10, wx = wr % 10;
                    int y = wy * 16 + (q >> 4), xx = wx * 16 + (q & 15);
                    of[((long)((bb * CH + y) * CW + xx)) * CC + col] = val + b0[col];
                }
            }
        }
    }
}

// ---------------------------------------------------------------------------
// Attention v5: attn4 math (no-max exp2 softmax, slot-consistent P/V, bitmask
// border masking) + explicit software pipelining: one-tile-ahead bias
// double-buffer (bA/bB), bigger register budget, division-free incremental KV
// pointers, mid-chunk LDS write-back, vectorized gate/store epilogue.
// ---------------------------------------------------------------------------
__global__ __launch_bounds__(256, 3)
void attn5_k(const __bf16* __restrict__ Q, const __bf16* __restrict__ KV,
             const __bf16* __restrict__ G, const float* __restrict__ BTf,
             const u32* __restrict__ MT, __bf16* __restrict__ Y)
{
    __shared__ __bf16 Ks[2][64][44];   // [buf][kv][d]
    __shared__ __bf16 Vt[2][32][76];   // [buf][d][kv]

    // XCD swizzle: all 6 heads of a window on one XCD.
    const int bid = blockIdx.x;            // 1200 = 8 * 150
    const int xs = bid & 7, ii = bid >> 3;
    const int win = xs * 25 + ii / 6;
    const int head = ii % 6;

    const int bb = win / 100, wr = win % 100, wy = wr / 10, wx = wr % 10;
    const int cy = (wy == 0) ? 0 : ((wy == 9) ? 2 : 1);
    const int cx = (wx == 0) ? 0 : ((wx == 9) ? 2 : 1);
    const int cls = cy * 3 + cx;
    const int t = threadIdx.x, lane = t & 63, wv = t >> 6;
    const int l31 = lane & 31, hi = lane >> 5;

    bf16x8 qf[2][2];
    const __bf16* qb = Q + ((long)win * CNQ + wv * 64) * CC + head * CD;
#pragma unroll
    for (int qt = 0; qt < 2; ++qt)
#pragma unroll
        for (int dk = 0; dk < 2; ++dk)
            qf[qt][dk] = *(const bf16x8*)(qb + (qt * 32 + l31) * CC + dk * 16 + hi * 8);

    f32x16 o[2] = {};
    float srun[2] = {0.f, 0.f};

    const int srow = t >> 2, sseg = t & 3;

    // incremental KV pointer (position = ch*64 + srow in the 24x24 patch)
    int oy0 = srow / 24;
    int oxs = srow - oy0 * 24;
    const __bf16* kvp = KV
        + ((long)((bb * CPH + wy * 16 + oy0) * CPH + wx * 16 + oxs)) * 384
        + head * CD + sseg * 8;

    // --- prologue: stage chunk 0, load bias(ktg=0) ---
    {
        bf16x8 kr = *(const bf16x8*)kvp;
        bf16x8 vr = *(const bf16x8*)(kvp + CC);
        *(bf16x8*)&Ks[0][srow][sseg * 8] = kr;
#pragma unroll
        for (int j = 0; j < 8; ++j) Vt[0][sseg * 8 + j][srow] = vr[j];
    }
    const float* btb = BTf + ((long)((head * 8 + wv * 2) * 18) * 64) * 16;
    BiasT bA0 = load_bias(btb + (long)lane * 16);
    BiasT bA1 = load_bias(btb + (long)18 * 1024 + (long)lane * 16);
    BiasT bB0, bB1;
    __syncthreads();

    auto tile = [&](int ktg, int nktg, int curbuf, int kt,
                    BiasT& c0, BiasT& c1, BiasT& n0, BiasT& n1) {
        // K fragments (critical path first)
        bf16x8 kf0 = *(const bf16x8*)&Ks[curbuf][kt * 32 + l31][hi * 8];
        bf16x8 kf1 = *(const bf16x8*)&Ks[curbuf][kt * 32 + l31][16 + hi * 8];
        f32x16 st0 = b2v(c0), st1 = b2v(c1);
        __builtin_amdgcn_s_setprio(1);
        st0 = MFMA32(kf0, qf[0][0], st0);
        st0 = MFMA32(kf1, qf[0][1], st0);
        st1 = MFMA32(kf0, qf[1][0], st1);
        st1 = MFMA32(kf1, qf[1][1], st1);
        __builtin_amdgcn_s_setprio(0);

        // V fragments (PV lead time covers LDS latency)
        bf16x4 v00 = *(const bf16x4*)&Vt[curbuf][l31][kt * 32 + 4 * hi];
        bf16x4 v01 = *(const bf16x4*)&Vt[curbuf][l31][kt * 32 + 8 + 4 * hi];
        bf16x4 v10 = *(const bf16x4*)&Vt[curbuf][l31][kt * 32 + 16 + 4 * hi];
        bf16x4 v11 = *(const bf16x4*)&Vt[curbuf][l31][kt * 32 + 24 + 4 * hi];
        bf16x8 vf0, vf1;
#pragma unroll
        for (int j = 0; j < 4; ++j) {
            vf0[j] = v00[j]; vf0[4 + j] = v01[j];
            vf1[j] = v10[j]; vf1[4 + j] = v11[j];
        }

        // prefetch NEXT tile's bias (consumed one tile later)
        n0 = load_bias(btb + (long)nktg * 1024 + (long)lane * 16);
        n1 = load_bias(btb + (long)(18 + nktg) * 1024 + (long)lane * 16);

        // border mask (block-uniform predicate)
        const bool needm = (cx != 1) || (cy == 0 && ktg < 3) || (cy == 2 && ktg >= 15);
        u32 m = 0xFFFFFFFFu;
        if (needm) m = MT[(cls * 18 + ktg) * 64 + lane];

        float p0[16], p1[16];
#pragma unroll
        for (int r = 0; r < 16; ++r) p0[r] = exp2f(st0[r]);
#pragma unroll
        for (int r = 0; r < 16; ++r) p1[r] = exp2f(st1[r]);
        if (needm) {
#pragma unroll
            for (int r = 0; r < 16; ++r) {
                p0[r] = (m & (1u << r)) ? p0[r] : 0.0f;
                p1[r] = (m & (1u << r)) ? p1[r] : 0.0f;
            }
        }
        float s0 = 0.f, s1 = 0.f;
#pragma unroll
        for (int r = 0; r < 16; ++r) { s0 += p0[r]; s1 += p1[r]; }
        srun[0] += s0; srun[1] += s1;

        u32 a0 = pack_bf16(p0[0], p0[1]),   a1 = pack_bf16(p0[2], p0[3]);
        u32 a2 = pack_bf16(p0[4], p0[5]),   a3 = pack_bf16(p0[6], p0[7]);
        u32 a4 = pack_bf16(p0[8], p0[9]),   a5 = pack_bf16(p0[10], p0[11]);
        u32 a6 = pack_bf16(p0[12], p0[13]), a7 = pack_bf16(p0[14], p0[15]);
        u32 b4_ = pack_bf16(p1[8], p1[9]),  b5 = pack_bf16(p1[10], p1[11]);
        u32 b0_ = pack_bf16(p1[0], p1[1]),  b1_ = pack_bf16(p1[2], p1[3]);
        u32 b2_ = pack_bf16(p1[4], p1[5]),  b3_ = pack_bf16(p1[6], p1[7]);
        u32 b6 = pack_bf16(p1[12], p1[13]), b7 = pack_bf16(p1[14], p1[15]);
        u32 pw00[4] = {a0, a1, a2, a3};
        u32 pw01[4] = {a4, a5, a6, a7};
        u32 pw10[4] = {b0_, b1_, b2_, b3_};
        u32 pw11[4] = {b4_, b5, b6, b7};
        bf16x8 pa00 = __builtin_bit_cast(bf16x8, *(ulonglong2*)pw00);
        bf16x8 pa01 = __builtin_bit_cast(bf16x8, *(ulonglong2*)pw01);
        bf16x8 pa10 = __builtin_bit_cast(bf16x8, *(ulonglong2*)pw10);
        bf16x8 pa11 = __builtin_bit_cast(bf16x8, *(ulonglong2*)pw11);

        __builtin_amdgcn_s_setprio(1);
        o[0] = MFMA32(vf0, pa00, o[0]);
        o[0] = MFMA32(vf1, pa01, o[0]);
        o[1] = MFMA32(vf0, pa10, o[1]);
        o[1] = MFMA32(vf1, pa11, o[1]);
        __builtin_amdgcn_s_setprio(0);
    };

    for (int ch = 0; ch < 9; ++ch) {
        const int cur = ch & 1;
        bf16x8 kr, vr;
        if (ch < 8) {   // advance pointer by 64 kv positions, issue loads early
            int nox = oxs + 16;
            bool wrap = nox >= 24;
            oxs = wrap ? nox - 24 : nox;
            kvp += (long)(wrap ? 496 : 352) * 384;
            kr = *(const bf16x8*)kvp;
            vr = *(const bf16x8*)(kvp + CC);
        }

        tile(ch * 2, ch * 2 + 1, cur, 0, bA0, bA1, bB0, bB1);

        if (ch < 8) {   // write-late staging, drains during kt1 compute
            *(bf16x8*)&Ks[cur ^ 1][srow][sseg * 8] = kr;
#pragma unroll
            for (int j = 0; j < 8; ++j) Vt[cur ^ 1][sseg * 8 + j][srow] = vr[j];
        }

        int nk = ch * 2 + 2; if (nk > 17) nk = 17;
        tile(ch * 2 + 1, nk, cur, 1, bB0, bB1, bA0, bA1);
        __syncthreads();
    }

    // --- epilogue: cross-half sum, normalize, gate, vectorized store ---
#pragma unroll
    for (int qt = 0; qt < 2; ++qt) {
        float sq = srun[qt] + __shfl_xor(srun[qt], 32);
        float rs = 1.0f / sq;
        long base = ((long)win * CNQ + wv * 64 + qt * 32 + l31) * CC + head * CD;
        const __bf16* gp = G + base;
        __bf16* yp = Y + base;
#pragma unroll
        for (int g = 0; g < 4; ++g) {
            bf16x4 gv = *(const bf16x4*)(gp + g * 8 + 4 * hi);
            bf16x4 ov;
#pragma unroll
            for (int j = 0; j < 4; ++j)
                ov[j] = (__bf16)(o[qt][g * 4 + j] * rs * (float)gv[j]);
            *(bf16x4*)(yp + g * 8 + 4 * hi) = ov;
        }
    }
}

// ---------------------------------------------------------------------------
extern "C" void kernel_launch(void* const* d_in, const int* in_sizes, int n_in,
                              void* d_out, int out_size, void* d_ws, size_t ws_size,
                              hipStream_t stream)
{
    (void)in_sizes; (void)n_in; (void)out_size; (void)ws_size;
    const float* x    = (const float*)d_in[0];
    const int*   rpi  = (const int*)  d_in[1];
    // d_in[2] = attn_mask (recomputed analytically)
    const float* q_w  = (const float*)d_in[3];
    const float* q_b  = (const float*)d_in[4];
    const float* kv_w = (const float*)d_in[5];
    const float* kv_b = (const float*)d_in[6];
    const float* btab = (const float*)d_in[7];
    const float* g_w  = (const float*)d_in[8];
    const float* g_b  = (const float*)d_in[9];
    const float* p_w  = (const float*)d_in[10];
    const float* p_b  = (const float*)d_in[11];
    float* out = (float*)d_out;

    char* ws = (char*)d_ws;
    __bf16* Qb  = (__bf16*)(ws);                  // 19,660,800 B
    __bf16* KVb = (__bf16*)(ws + 19660800);       // 43,352,064 B
    __bf16* Gb  = (__bf16*)(ws + 63012864);       // 19,660,800 B
    __bf16* Yb  = (__bf16*)(ws + 82673664);       // 19,660,800 B
    float*  BTf = (float*)(ws + 102334464);       // 3,538,944 B
    u32*    MT  = (u32*)(ws + 105873408);         // 41,472 B

    biasf_k<<<216, 256, 0, stream>>>(rpi, btab, BTf);
    mask_k<<<41, 256, 0, stream>>>(MT);
    gemm_k<0><<<dim3(800, 6), 256, 0, stream>>>(x, nullptr, q_w, g_w, q_b, g_b,
                                                Qb, Gb, nullptr);
    gemm_k<1><<<dim3(882, 6), 256, 0, stream>>>(x, nullptr, kv_w, nullptr, kv_b, nullptr,
                                                KVb, nullptr, nullptr);
    attn5_k<<<1200, 256, 0, stream>>>(Qb, KVb, Gb, BTf, MT, Yb);
    gemm_k<2><<<dim3(800, 3), 256, 0, stream>>>(nullptr, Yb, p_w, nullptr, p_b, nullptr,
                                                nullptr, nullptr, out);
}

// Round 6
// 195.993 us; speedup vs baseline: 2.1823x; 1.1459x over previous
//
#include <hip/hip_runtime.h>
#include <hip/hip_bf16.h>
#include <stdint.h>

typedef __bf16 bf16x8  __attribute__((ext_vector_type(8)));
typedef __bf16 bf16x4  __attribute__((ext_vector_type(4)));
typedef __bf16 bf16x16 __attribute__((ext_vector_type(16)));
typedef float  f32x4   __attribute__((ext_vector_type(4)));
typedef float  f32x16  __attribute__((ext_vector_type(16)));
typedef uint32_t u32;

#define MFMA16(a, b, c) __builtin_amdgcn_mfma_f32_16x16x32_bf16((a), (b), (c), 0, 0, 0)
#define MFMA32(a, b, c) __builtin_amdgcn_mfma_f32_32x32x16_bf16((a), (b), (c), 0, 0, 0)

constexpr int CH = 160, CW = 160, CC = 192, CHEADS = 6, CD = 32;
constexpr int CNQ = 256, CNKV = 576, CPH = 168;
constexpr float LOG2E = 1.44269504088896340736f;
constexpr float QSCALE_L2E = 0.17677669529663687f * 1.44269504088896340736f;

// ---------------------------------------------------------------------------
// bf16 bias table (1.77 MB, L2-resident):
// bth[((head*8 + qtg)*18 + ktg)*64 + lane][16]
// ---------------------------------------------------------------------------
__global__ __launch_bounds__(256)
void biash_k(const int* __restrict__ rpi, const float* __restrict__ tab,
             __bf16* __restrict__ bth)
{
    int idx = blockIdx.x * 256 + threadIdx.x;  // 55296
    int lane = idx & 63;
    int rest = idx >> 6;
    int ktg = rest % 18; rest /= 18;
    int qtg = rest & 7;
    int head = rest >> 3;
    int l31 = lane & 31, hi = lane >> 5;
    int q = qtg * 32 + l31;

    bf16x16 o16;
#pragma unroll
    for (int g = 0; g < 4; ++g) {
        int4 ri = *(const int4*)(rpi + q * CNKV + ktg * 32 + 4 * hi + g * 8);
        o16[g * 4 + 0] = (__bf16)(tab[ri.x * CHEADS + head] * LOG2E);
        o16[g * 4 + 1] = (__bf16)(tab[ri.y * CHEADS + head] * LOG2E);
        o16[g * 4 + 2] = (__bf16)(tab[ri.z * CHEADS + head] * LOG2E);
        o16[g * 4 + 3] = (__bf16)(tab[ri.w * CHEADS + head] * LOG2E);
    }
    *(bf16x16*)(bth + (long)idx * 16) = o16;
}

// ---------------------------------------------------------------------------
// Validity bitmask MT[cls 9][ktg 18][lane 64]
// ---------------------------------------------------------------------------
__global__ __launch_bounds__(256)
void mask_k(u32* __restrict__ mt)
{
    int idx = blockIdx.x * 256 + threadIdx.x;  // 10368
    if (idx >= 9 * 18 * 64) return;
    int lane = idx & 63;
    int rest = idx >> 6;
    int ktg = rest % 18;
    int cls = rest / 18;
    int cy = cls / 3, cx = cls % 3;
    int hi = lane >> 5;
    u32 m = 0;
#pragma unroll
    for (int r = 0; r < 16; ++r) {
        int kv = ktg * 32 + 4 * hi + (r & 3) + 8 * (r >> 2);
        int oy = kv / 24, ox = kv - oy * 24;
        bool vy = (cy == 0) ? (oy >= 4) : ((cy == 2) ? (oy < 20) : true);
        bool vx = (cx == 0) ? (ox >= 4) : ((cx == 2) ? (ox < 20) : true);
        if (vy && vx) m |= (1u << r);
    }
    mt[idx] = m;
}

// ---------------------------------------------------------------------------
// Weight transpose+fuse: Wt[768][192] = [q_w*s | g_w | kv_w]^T bf16,
// Wp[192][192] = p_w^T bf16, b768 = [q_b*s | g_b | kv_b] f32, pb = p_b f32.
// ---------------------------------------------------------------------------
__global__ __launch_bounds__(256)
void wtrans_k(const float* __restrict__ q_w, const float* __restrict__ g_w,
              const float* __restrict__ kv_w, const float* __restrict__ p_w,
              const float* __restrict__ q_b, const float* __restrict__ g_b,
              const float* __restrict__ kv_b, const float* __restrict__ p_b,
              __bf16* __restrict__ Wt, __bf16* __restrict__ Wp,
              float* __restrict__ b768, float* __restrict__ pb)
{
    int idx = blockIdx.x * 256 + threadIdx.x;
    if (idx < 147456) {
        int n = idx / 192, k = idx - n * 192;
        float v;
        if (n < 192)      v = q_w[k * 192 + n] * QSCALE_L2E;
        else if (n < 384) v = g_w[k * 192 + (n - 192)];
        else              v = kv_w[k * 384 + (n - 384)];
        Wt[idx] = (__bf16)v;
    } else if (idx < 184320) {
        int j = idx - 147456;
        int n = j / 192, k = j - n * 192;
        Wp[j] = (__bf16)p_w[k * 192 + n];
    } else if (idx < 185280) {
        int j = idx - 184320;
        if (j < 192)      b768[j] = q_b[j] * QSCALE_L2E;
        else if (j < 384) b768[j] = g_b[j - 192];
        else if (j < 768) b768[j] = kv_b[j - 384];
        else              pb[j - 768] = p_b[j - 768];
    }
}

// ---------------------------------------------------------------------------
// Fill KV pad rows with kv_b (bf16).
// ---------------------------------------------------------------------------
__global__ __launch_bounds__(256)
void padfill_k(const float* __restrict__ kv_b, __bf16* __restrict__ KVb)
{
    int tid = blockIdx.x * 256 + threadIdx.x;   // 5248 rows * 48 segs = 251904
    int row = tid / 48, seg = tid - row * 48;
    int bb = row / 2624, rr = row - bb * 2624;
    int py, px;
    if (rr < 672)       { py = rr / 168;               px = rr % 168; }
    else if (rr < 1344) { int r2 = rr - 672; py = 164 + r2 / 168; px = r2 % 168; }
    else                { int rm = rr - 1344; py = 4 + rm / 8; int q = rm & 7;
                          px = (q < 4) ? q : 160 + q; }
    bf16x8 v;
#pragma unroll
    for (int j = 0; j < 8; ++j) v[j] = (__bf16)kv_b[seg * 8 + j];
    *(bf16x8*)(KVb + ((long)((bb * CPH + py) * CPH + px)) * 384 + seg * 8) = v;
}

// ---------------------------------------------------------------------------
// Fused QGKV GEMM: M=51200 image rows, N=768 (Q|G|KV), K=192.
// BM=BN=BK=64, reg-staged XOR-swizzled [64][64] LDS, double-buffered.
// Epilogue scatters: Q,G -> window layout bf16; KV -> padded-image bf16.
// ---------------------------------------------------------------------------
__global__ __launch_bounds__(256)
void gemm_f_k(const float* __restrict__ x, const __bf16* __restrict__ Wt,
              const float* __restrict__ b768,
              __bf16* __restrict__ Qb, __bf16* __restrict__ Gb,
              __bf16* __restrict__ KVb)
{
    __shared__ __bf16 As[2][4096];
    __shared__ __bf16 Bs[2][4096];

    const int bid = blockIdx.x;                 // 9600 = 8 * 1200
    const int v = (bid & 7) * 1200 + (bid >> 3);
    const int bm = v / 12, bn = v - bm * 12;

    const int t = threadIdx.x, lane = t & 63, wv = t >> 6;
    const int l15 = lane & 15, l4 = lane >> 4;
    const int row = t >> 2, gp = t & 3;
    const int swz = row & 7;
    const int d0 = row * 64 + ((2 * gp) ^ swz) * 8;
    const int d1 = row * 64 + ((2 * gp + 1) ^ swz) * 8;

    const float*  asrc = x  + (long)(bm * 64 + row) * 192 + gp * 16;
    const __bf16* bsrc = Wt + (long)(bn * 64 + row) * 192 + gp * 16;

    float4 fa0, fa1, fa2, fa3;
    bf16x8 wb0, wb1;
    auto ld = [&](int kt) {
        const float* a = asrc + kt * 64;
        fa0 = ((const float4*)a)[0]; fa1 = ((const float4*)a)[1];
        fa2 = ((const float4*)a)[2]; fa3 = ((const float4*)a)[3];
        wb0 = *(const bf16x8*)(bsrc + kt * 64);
        wb1 = *(const bf16x8*)(bsrc + kt * 64 + 8);
    };
    auto st = [&](int buf) {
        bf16x8 g0, g1;
        g0[0] = (__bf16)fa0.x; g0[1] = (__bf16)fa0.y; g0[2] = (__bf16)fa0.z; g0[3] = (__bf16)fa0.w;
        g0[4] = (__bf16)fa1.x; g0[5] = (__bf16)fa1.y; g0[6] = (__bf16)fa1.z; g0[7] = (__bf16)fa1.w;
        g1[0] = (__bf16)fa2.x; g1[1] = (__bf16)fa2.y; g1[2] = (__bf16)fa2.z; g1[3] = (__bf16)fa2.w;
        g1[4] = (__bf16)fa3.x; g1[5] = (__bf16)fa3.y; g1[6] = (__bf16)fa3.z; g1[7] = (__bf16)fa3.w;
        *(bf16x8*)&As[buf][d0] = g0;
        *(bf16x8*)&As[buf][d1] = g1;
        *(bf16x8*)&Bs[buf][d0] = wb0;
        *(bf16x8*)&Bs[buf][d1] = wb1;
    };

    const int qm = (wv >> 1) * 32, qn = (wv & 1) * 32;
    f32x4 acc[2][2];
#pragma unroll
    for (int i = 0; i < 2; ++i)
#pragma unroll
        for (int j = 0; j < 2; ++j) acc[i][j] = f32x4{0.f, 0.f, 0.f, 0.f};

    ld(0);
    for (int kt = 0; kt < 3; ++kt) {
        const int buf = kt & 1;
        st(buf);
        if (kt < 2) ld(kt + 1);
        __syncthreads();
#pragma unroll
        for (int s = 0; s < 2; ++s) {
            bf16x8 af[2], bfr[2];
#pragma unroll
            for (int mi = 0; mi < 2; ++mi)
                af[mi] = *(const bf16x8*)&As[buf][(qm + mi * 16 + l15) * 64 +
                                                 (((s * 4 + l4) ^ (l15 & 7)) * 8)];
#pragma unroll
            for (int ni = 0; ni < 2; ++ni)
                bfr[ni] = *(const bf16x8*)&Bs[buf][(qn + ni * 16 + l15) * 64 +
                                                   (((s * 4 + l4) ^ (l15 & 7)) * 8)];
#pragma unroll
            for (int mi = 0; mi < 2; ++mi)
#pragma unroll
                for (int ni = 0; ni < 2; ++ni)
                    acc[mi][ni] = MFMA16(af[mi], bfr[ni], acc[mi][ni]);
        }
        __syncthreads();
    }

#pragma unroll
    for (int mi = 0; mi < 2; ++mi) {
#pragma unroll
        for (int r = 0; r < 4; ++r) {
            int rowg = bm * 64 + qm + mi * 16 + l4 * 4 + r;
            int bb = rowg / 25600, rr = rowg - bb * 25600;
            int y = rr / 160, xx = rr - y * 160;
            int win = bb * 100 + (y >> 4) * 10 + (xx >> 4);
            long widx = ((long)win * 256 + (y & 15) * 16 + (xx & 15)) * 192;
            long kidx = ((long)((bb * CPH + y + 4) * CPH + (xx + 4))) * 384;
#pragma unroll
            for (int ni = 0; ni < 2; ++ni) {
                int cg = bn * 64 + qn + ni * 16 + l15;
                float val = acc[mi][ni][r] + b768[cg];
                if (cg < 192)       Qb[widx + cg] = (__bf16)val;
                else if (cg < 384)  Gb[widx + cg - 192] = (__bf16)val;
                else                KVb[kidx + cg - 384] = (__bf16)val;
            }
        }
    }
}

// ---------------------------------------------------------------------------
// Projection GEMM: M=51200 window rows (Yb), N=192, K=192; out f32 image.
// ---------------------------------------------------------------------------
__global__ __launch_bounds__(256)
void gemm_p_k(const __bf16* __restrict__ Yb, const __bf16* __restrict__ Wp,
              const float* __restrict__ pb, float* __restrict__ of)
{
    __shared__ __bf16 As[2][4096];
    __shared__ __bf16 Bs[2][4096];

    const int bid = blockIdx.x;                 // 2400 = 8 * 300
    const int v = (bid & 7) * 300 + (bid >> 3);
    const int bm = v / 3, bn = v - bm * 3;

    const int t = threadIdx.x, lane = t & 63, wv = t >> 6;
    const int l15 = lane & 15, l4 = lane >> 4;
    const int row = t >> 2, gp = t & 3;
    const int swz = row & 7;
    const int d0 = row * 64 + ((2 * gp) ^ swz) * 8;
    const int d1 = row * 64 + ((2 * gp + 1) ^ swz) * 8;

    const __bf16* asrc = Yb + (long)(bm * 64 + row) * 192 + gp * 16;
    const __bf16* bsrc = Wp + (long)(bn * 64 + row) * 192 + gp * 16;

    bf16x8 a0, a1, wb0, wb1;
    auto ld = [&](int kt) {
        a0  = *(const bf16x8*)(asrc + kt * 64);
        a1  = *(const bf16x8*)(asrc + kt * 64 + 8);
        wb0 = *(const bf16x8*)(bsrc + kt * 64);
        wb1 = *(const bf16x8*)(bsrc + kt * 64 + 8);
    };
    auto st = [&](int buf) {
        *(bf16x8*)&As[buf][d0] = a0;
        *(bf16x8*)&As[buf][d1] = a1;
        *(bf16x8*)&Bs[buf][d0] = wb0;
        *(bf16x8*)&Bs[buf][d1] = wb1;
    };

    const int qm = (wv >> 1) * 32, qn = (wv & 1) * 32;
    f32x4 acc[2][2];
#pragma unroll
    for (int i = 0; i < 2; ++i)
#pragma unroll
        for (int j = 0; j < 2; ++j) acc[i][j] = f32x4{0.f, 0.f, 0.f, 0.f};

    ld(0);
    for (int kt = 0; kt < 3; ++kt) {
        const int buf = kt & 1;
        st(buf);
        if (kt < 2) ld(kt + 1);
        __syncthreads();
#pragma unroll
        for (int s = 0; s < 2; ++s) {
            bf16x8 af[2], bfr[2];
#pragma unroll
            for (int mi = 0; mi < 2; ++mi)
                af[mi] = *(const bf16x8*)&As[buf][(qm + mi * 16 + l15) * 64 +
                                                 (((s * 4 + l4) ^ (l15 & 7)) * 8)];
#pragma unroll
            for (int ni = 0; ni < 2; ++ni)
                bfr[ni] = *(const bf16x8*)&Bs[buf][(qn + ni * 16 + l15) * 64 +
                                                   (((s * 4 + l4) ^ (l15 & 7)) * 8)];
#pragma unroll
            for (int mi = 0; mi < 2; ++mi)
#pragma unroll
                for (int ni = 0; ni < 2; ++ni)
                    acc[mi][ni] = MFMA16(af[mi], bfr[ni], acc[mi][ni]);
        }
        __syncthreads();
    }

#pragma unroll
    for (int mi = 0; mi < 2; ++mi) {
#pragma unroll
        for (int r = 0; r < 4; ++r) {
            int rowg = bm * 64 + qm + mi * 16 + l4 * 4 + r;   // window row
            int win = rowg >> 8, q = rowg & 255;
            int bb = win / 100, wr = win % 100;
            int y = (wr / 10) * 16 + (q >> 4), xx = (wr % 10) * 16 + (q & 15);
            long oidx = ((long)((bb * CH + y) * CW + xx)) * 192;
#pragma unroll
            for (int ni = 0; ni < 2; ++ni) {
                int cg = bn * 64 + qn + ni * 16 + l15;
                of[oidx + cg] = acc[mi][ni][r] + pb[cg];
            }
        }
    }
}

// ---------------------------------------------------------------------------
// Attention v6: bf16 bias double-buffer prefetched at tile top + sched_barrier
// fence (anti-sink); chunk-hoisted K/V fragment reads; otherwise attn5 math.
// ---------------------------------------------------------------------------
__global__ __launch_bounds__(256)
void attn6_k(const __bf16* __restrict__ Q, const __bf16* __restrict__ KV,
             const __bf16* __restrict__ G, const __bf16* __restrict__ BTh,
             const u32* __restrict__ MT, __bf16* __restrict__ Y)
{
    __shared__ __bf16 Ks[2][64][44];
    __shared__ __bf16 Vt[2][32][76];

    const int bid = blockIdx.x;            // 1200 = 8 * 150
    const int xs = bid & 7, ii = bid >> 3;
    const int win = xs * 25 + ii / 6;
    const int head = ii % 6;

    const int bb = win / 100, wr = win % 100, wy = wr / 10, wx = wr % 10;
    const int cy = (wy == 0) ? 0 : ((wy == 9) ? 2 : 1);
    const int cx = (wx == 0) ? 0 : ((wx == 9) ? 2 : 1);
    const int cls = cy * 3 + cx;
    const int t = threadIdx.x, lane = t & 63, wv = t >> 6;
    const int l31 = lane & 31, hi = lane >> 5;

    bf16x8 qf[2][2];
    const __bf16* qb = Q + ((long)win * CNQ + wv * 64) * CC + head * CD;
#pragma unroll
    for (int qt = 0; qt < 2; ++qt)
#pragma unroll
        for (int dk = 0; dk < 2; ++dk)
            qf[qt][dk] = *(const bf16x8*)(qb + (qt * 32 + l31) * CC + dk * 16 + hi * 8);

    f32x16 o[2] = {};
    float srun[2] = {0.f, 0.f};

    const int srow = t >> 2, sseg = t & 3;
    int oy0 = srow / 24;
    int oxs = srow - oy0 * 24;
    const __bf16* kvp = KV
        + ((long)((bb * CPH + wy * 16 + oy0) * CPH + wx * 16 + oxs)) * 384
        + head * CD + sseg * 8;

    {
        bf16x8 kr = *(const bf16x8*)kvp;
        bf16x8 vr = *(const bf16x8*)(kvp + CC);
        *(bf16x8*)&Ks[0][srow][sseg * 8] = kr;
#pragma unroll
        for (int j = 0; j < 8; ++j) Vt[0][sseg * 8 + j][srow] = vr[j];
    }
    const __bf16* btb = BTh + (long)((head * 8 + wv * 2) * 18) * 1024;
    bf16x16 bA0 = *(const bf16x16*)(btb + (long)lane * 16);
    bf16x16 bA1 = *(const bf16x16*)(btb + 18432 + (long)lane * 16);
    bf16x16 bB0, bB1;
    __syncthreads();

    auto tile = [&](int ktg, int nktg, const bf16x8* kf, const bf16x8* vf,
                    bf16x16& c0, bf16x16& c1, bf16x16& n0, bf16x16& n1) {
        // prefetch NEXT tile's bias FIRST, then fence against sinking
        n0 = *(const bf16x16*)(btb + (long)nktg * 1024 + (long)lane * 16);
        n1 = *(const bf16x16*)(btb + 18432 + (long)nktg * 1024 + (long)lane * 16);
        __builtin_amdgcn_sched_barrier(0);

        f32x16 st0, st1;
#pragma unroll
        for (int r = 0; r < 16; ++r) { st0[r] = (float)c0[r]; st1[r] = (float)c1[r]; }
        __builtin_amdgcn_s_setprio(1);
        st0 = MFMA32(kf[0], qf[0][0], st0);
        st0 = MFMA32(kf[1], qf[0][1], st0);
        st1 = MFMA32(kf[0], qf[1][0], st1);
        st1 = MFMA32(kf[1], qf[1][1], st1);
        __builtin_amdgcn_s_setprio(0);

        const bool needm = (cx != 1) || (cy == 0 && ktg < 3) || (cy == 2 && ktg >= 15);
        u32 m = 0xFFFFFFFFu;
        if (needm) m = MT[(cls * 18 + ktg) * 64 + lane];

        float p0[16], p1[16];
#pragma unroll
        for (int r = 0; r < 16; ++r) p0[r] = exp2f(st0[r]);
#pragma unroll
        for (int r = 0; r < 16; ++r) p1[r] = exp2f(st1[r]);
        if (needm) {
#pragma unroll
            for (int r = 0; r < 16; ++r) {
                p0[r] = (m & (1u << r)) ? p0[r] : 0.0f;
                p1[r] = (m & (1u << r)) ? p1[r] : 0.0f;
            }
        }
        float s0 = 0.f, s1 = 0.f;
#pragma unroll
        for (int r = 0; r < 16; ++r) { s0 += p0[r]; s1 += p1[r]; }
        srun[0] += s0; srun[1] += s1;

        bf16x8 pa00, pa01, pa10, pa11;
#pragma unroll
        for (int j = 0; j < 8; ++j) {
            pa00[j] = (__bf16)p0[j];     pa01[j] = (__bf16)p0[8 + j];
            pa10[j] = (__bf16)p1[j];     pa11[j] = (__bf16)p1[8 + j];
        }

        __builtin_amdgcn_s_setprio(1);
        o[0] = MFMA32(vf[0], pa00, o[0]);
        o[0] = MFMA32(vf[1], pa01, o[0]);
        o[1] = MFMA32(vf[0], pa10, o[1]);
        o[1] = MFMA32(vf[1], pa11, o[1]);
        __builtin_amdgcn_s_setprio(0);
    };

    for (int ch = 0; ch < 9; ++ch) {
        const int cur = ch & 1;
        bf16x8 kr, vr;
        if (ch < 8) {
            int nox = oxs + 16;
            bool wrap = nox >= 24;
            oxs = wrap ? nox - 24 : nox;
            kvp += (long)(wrap ? 496 : 352) * 384;
            kr = *(const bf16x8*)kvp;
            vr = *(const bf16x8*)(kvp + CC);
        }

        // chunk-hoisted LDS fragment reads (both tiles)
        bf16x8 kf[2][2], vf[2][2];
#pragma unroll
        for (int kt = 0; kt < 2; ++kt) {
            kf[kt][0] = *(const bf16x8*)&Ks[cur][kt * 32 + l31][hi * 8];
            kf[kt][1] = *(const bf16x8*)&Ks[cur][kt * 32 + l31][16 + hi * 8];
            bf16x4 v00 = *(const bf16x4*)&Vt[cur][l31][kt * 32 + 4 * hi];
            bf16x4 v01 = *(const bf16x4*)&Vt[cur][l31][kt * 32 + 8 + 4 * hi];
            bf16x4 v10 = *(const bf16x4*)&Vt[cur][l31][kt * 32 + 16 + 4 * hi];
            bf16x4 v11 = *(const bf16x4*)&Vt[cur][l31][kt * 32 + 24 + 4 * hi];
#pragma unroll
            for (int j = 0; j < 4; ++j) {
                vf[kt][0][j] = v00[j]; vf[kt][0][4 + j] = v01[j];
                vf[kt][1][j] = v10[j]; vf[kt][1][4 + j] = v11[j];
            }
        }

        tile(ch * 2, ch * 2 + 1, kf[0], vf[0], bA0, bA1, bB0, bB1);

        if (ch < 8) {
            *(bf16x8*)&Ks[cur ^ 1][srow][sseg * 8] = kr;
#pragma unroll
            for (int j = 0; j < 8; ++j) Vt[cur ^ 1][sseg * 8 + j][srow] = vr[j];
        }

        int nk = ch * 2 + 2; if (nk > 17) nk = 17;
        tile(ch * 2 + 1, nk, kf[1], vf[1], bB0, bB1, bA0, bA1);
        __syncthreads();
    }

#pragma unroll
    for (int qt = 0; qt < 2; ++qt) {
        float sq = srun[qt] + __shfl_xor(srun[qt], 32);
        float rs = 1.0f / sq;
        long base = ((long)win * CNQ + wv * 64 + qt * 32 + l31) * CC + head * CD;
        const __bf16* gp2 = G + base;
        __bf16* yp = Y + base;
#pragma unroll
        for (int g = 0; g < 4; ++g) {
            bf16x4 gv = *(const bf16x4*)(gp2 + g * 8 + 4 * hi);
            bf16x4 ov;
#pragma unroll
            for (int j = 0; j < 4; ++j)
                ov[j] = (__bf16)(o[qt][g * 4 + j] * rs * (float)gv[j]);
            *(bf16x4*)(yp + g * 8 + 4 * hi) = ov;
        }
    }
}

// ---------------------------------------------------------------------------
extern "C" void kernel_launch(void* const* d_in, const int* in_sizes, int n_in,
                              void* d_out, int out_size, void* d_ws, size_t ws_size,
                              hipStream_t stream)
{
    (void)in_sizes; (void)n_in; (void)out_size; (void)ws_size;
    const float* x    = (const float*)d_in[0];
    const int*   rpi  = (const int*)  d_in[1];
    // d_in[2] = attn_mask (recomputed analytically)
    const float* q_w  = (const float*)d_in[3];
    const float* q_b  = (const float*)d_in[4];
    const float* kv_w = (const float*)d_in[5];
    const float* kv_b = (const float*)d_in[6];
    const float* btab = (const float*)d_in[7];
    const float* g_w  = (const float*)d_in[8];
    const float* g_b  = (const float*)d_in[9];
    const float* p_w  = (const float*)d_in[10];
    const float* p_b  = (const float*)d_in[11];
    float* out = (float*)d_out;

    char* ws = (char*)d_ws;
    __bf16* Qb  = (__bf16*)(ws);                  // 19,660,800
    __bf16* KVb = (__bf16*)(ws + 19660800);       // 43,352,064
    __bf16* Gb  = (__bf16*)(ws + 63012864);       // 19,660,800
    __bf16* Yb  = (__bf16*)(ws + 82673664);       // 19,660,800
    __bf16* BTh = (__bf16*)(ws + 102334464);      // 1,769,472
    u32*    MT  = (u32*)   (ws + 104103936);      // 41,472
    __bf16* Wt  = (__bf16*)(ws + 104145408);      // 294,912
    __bf16* Wp  = (__bf16*)(ws + 104440320);      // 73,728
    float*  b768= (float*) (ws + 104514048);      // 3,072
    float*  pb  = (float*) (ws + 104517120);      // 768

    biash_k<<<216, 256, 0, stream>>>(rpi, btab, BTh);
    mask_k<<<41, 256, 0, stream>>>(MT);
    wtrans_k<<<724, 256, 0, stream>>>(q_w, g_w, kv_w, p_w, q_b, g_b, kv_b, p_b,
                                      Wt, Wp, b768, pb);
    padfill_k<<<984, 256, 0, stream>>>(kv_b, KVb);
    gemm_f_k<<<9600, 256, 0, stream>>>(x, Wt, b768, Qb, Gb, KVb);
    attn6_k<<<1200, 256, 0, stream>>>(Qb, KVb, Gb, BTh, MT, Yb);
    gemm_p_k<<<2400, 256, 0, stream>>>(Yb, Wp, pb, out);
}

// Round 7
// 155.887 us; speedup vs baseline: 2.7438x; 1.2573x over previous
//
#include <hip/hip_runtime.h>
#include <hip/hip_bf16.h>
#include <stdint.h>

typedef __bf16 bf16x8  __attribute__((ext_vector_type(8)));
typedef __bf16 bf16x4  __attribute__((ext_vector_type(4)));
typedef __bf16 bf16x16 __attribute__((ext_vector_type(16)));
typedef float  f32x4   __attribute__((ext_vector_type(4)));
typedef float  f32x16  __attribute__((ext_vector_type(16)));
typedef uint32_t u32;

#define MFMA16(a, b, c) __builtin_amdgcn_mfma_f32_16x16x32_bf16((a), (b), (c), 0, 0, 0)
#define MFMA32(a, b, c) __builtin_amdgcn_mfma_f32_32x32x16_bf16((a), (b), (c), 0, 0, 0)

constexpr int CH = 160, CW = 160, CC = 192, CHEADS = 6, CD = 32;
constexpr int CNQ = 256, CNKV = 576, CPH = 168;
constexpr float LOG2E = 1.44269504088896340736f;
constexpr float QSCALE_L2E = 0.17677669529663687f * 1.44269504088896340736f;

// ---------------------------------------------------------------------------
// bf16 bias table (1.77 MB, L2-resident):
// bth[((head*8 + qtg)*18 + ktg)*64 + lane][16]
// ---------------------------------------------------------------------------
__global__ __launch_bounds__(256)
void biash_k(const int* __restrict__ rpi, const float* __restrict__ tab,
             __bf16* __restrict__ bth)
{
    int idx = blockIdx.x * 256 + threadIdx.x;  // 55296
    int lane = idx & 63;
    int rest = idx >> 6;
    int ktg = rest % 18; rest /= 18;
    int qtg = rest & 7;
    int head = rest >> 3;
    int l31 = lane & 31, hi = lane >> 5;
    int q = qtg * 32 + l31;

    bf16x16 o16;
#pragma unroll
    for (int g = 0; g < 4; ++g) {
        int4 ri = *(const int4*)(rpi + q * CNKV + ktg * 32 + 4 * hi + g * 8);
        o16[g * 4 + 0] = (__bf16)(tab[ri.x * CHEADS + head] * LOG2E);
        o16[g * 4 + 1] = (__bf16)(tab[ri.y * CHEADS + head] * LOG2E);
        o16[g * 4 + 2] = (__bf16)(tab[ri.z * CHEADS + head] * LOG2E);
        o16[g * 4 + 3] = (__bf16)(tab[ri.w * CHEADS + head] * LOG2E);
    }
    *(bf16x16*)(bth + (long)idx * 16) = o16;
}

// ---------------------------------------------------------------------------
// Validity bitmask MT[cls 9][ktg 18][lane 64]
// ---------------------------------------------------------------------------
__global__ __launch_bounds__(256)
void mask_k(u32* __restrict__ mt)
{
    int idx = blockIdx.x * 256 + threadIdx.x;  // 10368
    if (idx >= 9 * 18 * 64) return;
    int lane = idx & 63;
    int rest = idx >> 6;
    int ktg = rest % 18;
    int cls = rest / 18;
    int cy = cls / 3, cx = cls % 3;
    int hi = lane >> 5;
    u32 m = 0;
#pragma unroll
    for (int r = 0; r < 16; ++r) {
        int kv = ktg * 32 + 4 * hi + (r & 3) + 8 * (r >> 2);
        int oy = kv / 24, ox = kv - oy * 24;
        bool vy = (cy == 0) ? (oy >= 4) : ((cy == 2) ? (oy < 20) : true);
        bool vx = (cx == 0) ? (ox >= 4) : ((cx == 2) ? (ox < 20) : true);
        if (vy && vx) m |= (1u << r);
    }
    mt[idx] = m;
}

// ---------------------------------------------------------------------------
// Weight transpose+fuse: Wt[768][192] = [q_w*s | g_w | kv_w]^T bf16,
// Wp[192][192] = p_w^T bf16, b768 = [q_b*s | g_b | kv_b] f32, pb = p_b f32.
// ---------------------------------------------------------------------------
__global__ __launch_bounds__(256)
void wtrans_k(const float* __restrict__ q_w, const float* __restrict__ g_w,
              const float* __restrict__ kv_w, const float* __restrict__ p_w,
              const float* __restrict__ q_b, const float* __restrict__ g_b,
              const float* __restrict__ kv_b, const float* __restrict__ p_b,
              __bf16* __restrict__ Wt, __bf16* __restrict__ Wp,
              float* __restrict__ b768, float* __restrict__ pb)
{
    int idx = blockIdx.x * 256 + threadIdx.x;
    if (idx < 147456) {
        int n = idx / 192, k = idx - n * 192;
        float v;
        if (n < 192)      v = q_w[k * 192 + n] * QSCALE_L2E;
        else if (n < 384) v = g_w[k * 192 + (n - 192)];
        else              v = kv_w[k * 384 + (n - 384)];
        Wt[idx] = (__bf16)v;
    } else if (idx < 184320) {
        int j = idx - 147456;
        int n = j / 192, k = j - n * 192;
        Wp[j] = (__bf16)p_w[k * 192 + n];
    } else if (idx < 185280) {
        int j = idx - 184320;
        if (j < 192)      b768[j] = q_b[j] * QSCALE_L2E;
        else if (j < 384) b768[j] = g_b[j - 192];
        else if (j < 768) b768[j] = kv_b[j - 384];
        else              pb[j - 768] = p_b[j - 768];
    }
}

// ---------------------------------------------------------------------------
// Fill KV pad rows with kv_b (bf16).
// ---------------------------------------------------------------------------
__global__ __launch_bounds__(256)
void padfill_k(const float* __restrict__ kv_b, __bf16* __restrict__ KVb)
{
    int tid = blockIdx.x * 256 + threadIdx.x;   // 5248 rows * 48 segs = 251904
    int row = tid / 48, seg = tid - row * 48;
    int bb = row / 2624, rr = row - bb * 2624;
    int py, px;
    if (rr < 672)       { py = rr / 168;               px = rr % 168; }
    else if (rr < 1344) { int r2 = rr - 672; py = 164 + r2 / 168; px = r2 % 168; }
    else                { int rm = rr - 1344; py = 4 + rm / 8; int q = rm & 7;
                          px = (q < 4) ? q : 160 + q; }
    bf16x8 v;
#pragma unroll
    for (int j = 0; j < 8; ++j) v[j] = (__bf16)kv_b[seg * 8 + j];
    *(bf16x8*)(KVb + ((long)((bb * CPH + py) * CPH + px)) * 384 + seg * 8) = v;
}

// ---------------------------------------------------------------------------
// Fused QGKV GEMM: M=51200 image rows, N=768 (Q|G|KV), K=192.
// BM=BN=BK=64, reg-staged XOR-swizzled [64][64] LDS, double-buffered.
// ---------------------------------------------------------------------------
__global__ __launch_bounds__(256)
void gemm_f_k(const float* __restrict__ x, const __bf16* __restrict__ Wt,
              const float* __restrict__ b768,
              __bf16* __restrict__ Qb, __bf16* __restrict__ Gb,
              __bf16* __restrict__ KVb)
{
    __shared__ __bf16 As[2][4096];
    __shared__ __bf16 Bs[2][4096];

    const int bid = blockIdx.x;                 // 9600 = 8 * 1200
    const int v = (bid & 7) * 1200 + (bid >> 3);
    const int bm = v / 12, bn = v - bm * 12;

    const int t = threadIdx.x, lane = t & 63, wv = t >> 6;
    const int l15 = lane & 15, l4 = lane >> 4;
    const int row = t >> 2, gp = t & 3;
    const int swz = row & 7;
    const int d0 = row * 64 + ((2 * gp) ^ swz) * 8;
    const int d1 = row * 64 + ((2 * gp + 1) ^ swz) * 8;

    const float*  asrc = x  + (long)(bm * 64 + row) * 192 + gp * 16;
    const __bf16* bsrc = Wt + (long)(bn * 64 + row) * 192 + gp * 16;

    float4 fa0, fa1, fa2, fa3;
    bf16x8 wb0, wb1;
    auto ld = [&](int kt) {
        const float* a = asrc + kt * 64;
        fa0 = ((const float4*)a)[0]; fa1 = ((const float4*)a)[1];
        fa2 = ((const float4*)a)[2]; fa3 = ((const float4*)a)[3];
        wb0 = *(const bf16x8*)(bsrc + kt * 64);
        wb1 = *(const bf16x8*)(bsrc + kt * 64 + 8);
    };
    auto st = [&](int buf) {
        bf16x8 g0, g1;
        g0[0] = (__bf16)fa0.x; g0[1] = (__bf16)fa0.y; g0[2] = (__bf16)fa0.z; g0[3] = (__bf16)fa0.w;
        g0[4] = (__bf16)fa1.x; g0[5] = (__bf16)fa1.y; g0[6] = (__bf16)fa1.z; g0[7] = (__bf16)fa1.w;
        g1[0] = (__bf16)fa2.x; g1[1] = (__bf16)fa2.y; g1[2] = (__bf16)fa2.z; g1[3] = (__bf16)fa2.w;
        g1[4] = (__bf16)fa3.x; g1[5] = (__bf16)fa3.y; g1[6] = (__bf16)fa3.z; g1[7] = (__bf16)fa3.w;
        *(bf16x8*)&As[buf][d0] = g0;
        *(bf16x8*)&As[buf][d1] = g1;
        *(bf16x8*)&Bs[buf][d0] = wb0;
        *(bf16x8*)&Bs[buf][d1] = wb1;
    };

    const int qm = (wv >> 1) * 32, qn = (wv & 1) * 32;
    f32x4 acc[2][2];
#pragma unroll
    for (int i = 0; i < 2; ++i)
#pragma unroll
        for (int j = 0; j < 2; ++j) acc[i][j] = f32x4{0.f, 0.f, 0.f, 0.f};

    ld(0);
    for (int kt = 0; kt < 3; ++kt) {
        const int buf = kt & 1;
        st(buf);
        if (kt < 2) ld(kt + 1);
        __syncthreads();
#pragma unroll
        for (int s = 0; s < 2; ++s) {
            bf16x8 af[2], bfr[2];
#pragma unroll
            for (int mi = 0; mi < 2; ++mi)
                af[mi] = *(const bf16x8*)&As[buf][(qm + mi * 16 + l15) * 64 +
                                                 (((s * 4 + l4) ^ (l15 & 7)) * 8)];
#pragma unroll
            for (int ni = 0; ni < 2; ++ni)
                bfr[ni] = *(const bf16x8*)&Bs[buf][(qn + ni * 16 + l15) * 64 +
                                                   (((s * 4 + l4) ^ (l15 & 7)) * 8)];
#pragma unroll
            for (int mi = 0; mi < 2; ++mi)
#pragma unroll
                for (int ni = 0; ni < 2; ++ni)
                    acc[mi][ni] = MFMA16(af[mi], bfr[ni], acc[mi][ni]);
        }
        __syncthreads();
    }

#pragma unroll
    for (int mi = 0; mi < 2; ++mi) {
#pragma unroll
        for (int r = 0; r < 4; ++r) {
            int rowg = bm * 64 + qm + mi * 16 + l4 * 4 + r;
            int bb = rowg / 25600, rr = rowg - bb * 25600;
            int y = rr / 160, xx = rr - y * 160;
            int win = bb * 100 + (y >> 4) * 10 + (xx >> 4);
            long widx = ((long)win * 256 + (y & 15) * 16 + (xx & 15)) * 192;
            long kidx = ((long)((bb * CPH + y + 4) * CPH + (xx + 4))) * 384;
#pragma unroll
            for (int ni = 0; ni < 2; ++ni) {
                int cg = bn * 64 + qn + ni * 16 + l15;
                float val = acc[mi][ni][r] + b768[cg];
                if (cg < 192)       Qb[widx + cg] = (__bf16)val;
                else if (cg < 384)  Gb[widx + cg - 192] = (__bf16)val;
                else                KVb[kidx + cg - 384] = (__bf16)val;
            }
        }
    }
}

// ---------------------------------------------------------------------------
// Projection GEMM: M=51200 window rows (Yb), N=192, K=192; out f32 image.
// ---------------------------------------------------------------------------
__global__ __launch_bounds__(256)
void gemm_p_k(const __bf16* __restrict__ Yb, const __bf16* __restrict__ Wp,
              const float* __restrict__ pb, float* __restrict__ of)
{
    __shared__ __bf16 As[2][4096];
    __shared__ __bf16 Bs[2][4096];

    const int bid = blockIdx.x;                 // 2400 = 8 * 300
    const int v = (bid & 7) * 300 + (bid >> 3);
    const int bm = v / 3, bn = v - bm * 3;

    const int t = threadIdx.x, lane = t & 63, wv = t >> 6;
    const int l15 = lane & 15, l4 = lane >> 4;
    const int row = t >> 2, gp = t & 3;
    const int swz = row & 7;
    const int d0 = row * 64 + ((2 * gp) ^ swz) * 8;
    const int d1 = row * 64 + ((2 * gp + 1) ^ swz) * 8;

    const __bf16* asrc = Yb + (long)(bm * 64 + row) * 192 + gp * 16;
    const __bf16* bsrc = Wp + (long)(bn * 64 + row) * 192 + gp * 16;

    bf16x8 a0, a1, wb0, wb1;
    auto ld = [&](int kt) {
        a0  = *(const bf16x8*)(asrc + kt * 64);
        a1  = *(const bf16x8*)(asrc + kt * 64 + 8);
        wb0 = *(const bf16x8*)(bsrc + kt * 64);
        wb1 = *(const bf16x8*)(bsrc + kt * 64 + 8);
    };
    auto st = [&](int buf) {
        *(bf16x8*)&As[buf][d0] = a0;
        *(bf16x8*)&As[buf][d1] = a1;
        *(bf16x8*)&Bs[buf][d0] = wb0;
        *(bf16x8*)&Bs[buf][d1] = wb1;
    };

    const int qm = (wv >> 1) * 32, qn = (wv & 1) * 32;
    f32x4 acc[2][2];
#pragma unroll
    for (int i = 0; i < 2; ++i)
#pragma unroll
        for (int j = 0; j < 2; ++j) acc[i][j] = f32x4{0.f, 0.f, 0.f, 0.f};

    ld(0);
    for (int kt = 0; kt < 3; ++kt) {
        const int buf = kt & 1;
        st(buf);
        if (kt < 2) ld(kt + 1);
        __syncthreads();
#pragma unroll
        for (int s = 0; s < 2; ++s) {
            bf16x8 af[2], bfr[2];
#pragma unroll
            for (int mi = 0; mi < 2; ++mi)
                af[mi] = *(const bf16x8*)&As[buf][(qm + mi * 16 + l15) * 64 +
                                                 (((s * 4 + l4) ^ (l15 & 7)) * 8)];
#pragma unroll
            for (int ni = 0; ni < 2; ++ni)
                bfr[ni] = *(const bf16x8*)&Bs[buf][(qn + ni * 16 + l15) * 64 +
                                                   (((s * 4 + l4) ^ (l15 & 7)) * 8)];
#pragma unroll
            for (int mi = 0; mi < 2; ++mi)
#pragma unroll
                for (int ni = 0; ni < 2; ++ni)
                    acc[mi][ni] = MFMA16(af[mi], bfr[ni], acc[mi][ni]);
        }
        __syncthreads();
    }

#pragma unroll
    for (int mi = 0; mi < 2; ++mi) {
#pragma unroll
        for (int r = 0; r < 4; ++r) {
            int rowg = bm * 64 + qm + mi * 16 + l4 * 4 + r;   // window row
            int win = rowg >> 8, q = rowg & 255;
            int bb = win / 100, wr = win % 100;
            int y = (wr / 10) * 16 + (q >> 4), xx = (wr % 10) * 16 + (q & 15);
            long oidx = ((long)((bb * CH + y) * CW + xx)) * 192;
#pragma unroll
            for (int ni = 0; ni < 2; ++ni) {
                int cg = bn * 64 + qn + ni * 16 + l15;
                of[oidx + cg] = acc[mi][ni][r] + pb[cg];
            }
        }
    }
}

// ---------------------------------------------------------------------------
// Attention v7: 512-thread blocks (8 waves x 32 q-rows), whole-window K + V^T
// staged to LDS ONCE, then an 18-tile main loop with ZERO barriers — waves
// free-run so resident waves actually hide bias/L2/exp2 latency. K-frag and
// bias prefetched one tile ahead in registers. Same verified math as v4-v6.
// ---------------------------------------------------------------------------
__global__ __launch_bounds__(512, 4)
void attn7_k(const __bf16* __restrict__ Q, const __bf16* __restrict__ KV,
             const __bf16* __restrict__ G, const __bf16* __restrict__ BTh,
             const u32* __restrict__ MT, __bf16* __restrict__ Y)
{
    __shared__ __bf16 Ks[576][36];   // 41,472 B; 72-B rows (~2-way max on b128)
    __shared__ __bf16 Vt[32][580];   // 37,120 B; 290-dword rows => conflict-free b64

    const int bid = blockIdx.x;      // 1200 = 8 * 150
    const int xs = bid & 7, ii = bid >> 3;
    const int win = xs * 25 + ii / 6;
    const int head = ii % 6;

    const int bb = win / 100, wr = win % 100, wy = wr / 10, wx = wr % 10;
    const int cy = (wy == 0) ? 0 : ((wy == 9) ? 2 : 1);
    const int cx = (wx == 0) ? 0 : ((wx == 9) ? 2 : 1);
    const int cls = cy * 3 + cx;
    const int t = threadIdx.x, lane = t & 63, wv = t >> 6;
    const int l31 = lane & 31, hi = lane >> 5;

    // ---- stage whole-window K and V^T (one time) ----
    {
        const int pos0 = t >> 3, seg = t & 7;
        int oy = pos0 / 24, ox = pos0 - oy * 24;
        const long rowbase = ((long)((bb * CPH + wy * 16) * CPH + wx * 16)) * 384
                             + head * CD;
        int pos = pos0;
#pragma unroll
        for (int r = 0; r < 9; ++r) {
            const __bf16* p = KV + rowbase + (long)(oy * CPH + ox) * 384;
            if (seg < 4) {
                bf16x8 k8 = *(const bf16x8*)(p + seg * 8);
                *(bf16x8*)&Ks[pos][seg * 8] = k8;
            } else {
                bf16x8 v8 = *(const bf16x8*)(p + 192 + (seg - 4) * 8);
#pragma unroll
                for (int j = 0; j < 8; ++j) Vt[(seg - 4) * 8 + j][pos] = v8[j];
            }
            pos += 64;
            oy += 2; ox += 16;
            if (ox >= 24) { ox -= 24; oy += 1; }
        }
    }

    // Q fragments (this wave's 32 q-rows)
    bf16x8 qf0, qf1;
    {
        const __bf16* qb = Q + ((long)win * CNQ + wv * 32 + l31) * CC + head * CD;
        qf0 = *(const bf16x8*)(qb + hi * 8);
        qf1 = *(const bf16x8*)(qb + 16 + hi * 8);
    }
    const __bf16* btb = BTh + (long)((head * 8 + wv) * 18) * 1024 + (long)lane * 16;
    bf16x16 bA = *(const bf16x16*)btb;

    __syncthreads();   // the ONLY barrier

    f32x16 o = {};
    float srun = 0.f;

    const char* kbase = (const char*)&Ks[0][0] + l31 * 72 + hi * 16;
    const char* vbase = (const char*)&Vt[0][0] + l31 * 1160 + hi * 8;

    bf16x8 kc0 = *(const bf16x8*)(kbase);
    bf16x8 kc1 = *(const bf16x8*)(kbase + 32);

    for (int tt = 0; tt < 18; ++tt) {
        // prefetch next tile's K frags (LDS) + bias (L2) one tile ahead
        bf16x8 kn0, kn1;
        bf16x16 bB;
        if (tt < 17) {
            const char* kn = kbase + (tt + 1) * 2304;
            kn0 = *(const bf16x8*)(kn);
            kn1 = *(const bf16x8*)(kn + 32);
            bB  = *(const bf16x16*)(btb + (long)(tt + 1) * 1024);
        }

        // V fragments for this tile (conflict-free b64 reads)
        const char* vp = vbase + tt * 64;
        bf16x4 v00 = *(const bf16x4*)(vp);
        bf16x4 v01 = *(const bf16x4*)(vp + 16);
        bf16x4 v10 = *(const bf16x4*)(vp + 32);
        bf16x4 v11 = *(const bf16x4*)(vp + 48);
        bf16x8 vf0, vf1;
#pragma unroll
        for (int j = 0; j < 4; ++j) {
            vf0[j] = v00[j]; vf0[4 + j] = v01[j];
            vf1[j] = v10[j]; vf1[4 + j] = v11[j];
        }

        // scores = bias + K^T Q
        f32x16 st;
#pragma unroll
        for (int r = 0; r < 16; ++r) st[r] = (float)bA[r];
        __builtin_amdgcn_s_setprio(1);
        st = MFMA32(kc0, qf0, st);
        st = MFMA32(kc1, qf1, st);
        __builtin_amdgcn_s_setprio(0);

        const bool needm = (cx != 1) || (cy == 0 && tt < 3) || (cy == 2 && tt >= 15);
        u32 m = 0xFFFFFFFFu;
        if (needm) m = MT[(cls * 18 + tt) * 64 + lane];

        float p[16];
#pragma unroll
        for (int r = 0; r < 16; ++r) p[r] = exp2f(st[r]);
        if (needm) {
#pragma unroll
            for (int r = 0; r < 16; ++r)
                p[r] = (m & (1u << r)) ? p[r] : 0.0f;
        }
        float s = 0.f;
#pragma unroll
        for (int r = 0; r < 16; ++r) s += p[r];
        srun += s;

        bf16x8 pa0, pa1;
#pragma unroll
        for (int j = 0; j < 8; ++j) {
            pa0[j] = (__bf16)p[j];
            pa1[j] = (__bf16)p[8 + j];
        }

        __builtin_amdgcn_s_setprio(1);
        o = MFMA32(vf0, pa0, o);
        o = MFMA32(vf1, pa1, o);
        __builtin_amdgcn_s_setprio(0);

        kc0 = kn0; kc1 = kn1; bA = bB;
    }

    // ---- epilogue: cross-half sum, normalize, gate, store ----
    srun += __shfl_xor(srun, 32);
    float rs = 1.0f / srun;
    long base = ((long)win * CNQ + wv * 32 + l31) * CC + head * CD;
    const __bf16* gp2 = G + base;
    __bf16* yp = Y + base;
#pragma unroll
    for (int g = 0; g < 4; ++g) {
        bf16x4 gv = *(const bf16x4*)(gp2 + g * 8 + 4 * hi);
        bf16x4 ov;
#pragma unroll
        for (int j = 0; j < 4; ++j)
            ov[j] = (__bf16)(o[g * 4 + j] * rs * (float)gv[j]);
        *(bf16x4*)(yp + g * 8 + 4 * hi) = ov;
    }
}

// ---------------------------------------------------------------------------
extern "C" void kernel_launch(void* const* d_in, const int* in_sizes, int n_in,
                              void* d_out, int out_size, void* d_ws, size_t ws_size,
                              hipStream_t stream)
{
    (void)in_sizes; (void)n_in; (void)out_size; (void)ws_size;
    const float* x    = (const float*)d_in[0];
    const int*   rpi  = (const int*)  d_in[1];
    // d_in[2] = attn_mask (recomputed analytically)
    const float* q_w  = (const float*)d_in[3];
    const float* q_b  = (const float*)d_in[4];
    const float* kv_w = (const float*)d_in[5];
    const float* kv_b = (const float*)d_in[6];
    const float* btab = (const float*)d_in[7];
    const float* g_w  = (const float*)d_in[8];
    const float* g_b  = (const float*)d_in[9];
    const float* p_w  = (const float*)d_in[10];
    const float* p_b  = (const float*)d_in[11];
    float* out = (float*)d_out;

    char* ws = (char*)d_ws;
    __bf16* Qb  = (__bf16*)(ws);                  // 19,660,800
    __bf16* KVb = (__bf16*)(ws + 19660800);       // 43,352,064
    __bf16* Gb  = (__bf16*)(ws + 63012864);       // 19,660,800
    __bf16* Yb  = (__bf16*)(ws + 82673664);       // 19,660,800
    __bf16* BTh = (__bf16*)(ws + 102334464);      // 1,769,472
    u32*    MT  = (u32*)   (ws + 104103936);      // 41,472
    __bf16* Wt  = (__bf16*)(ws + 104145408);      // 294,912
    __bf16* Wp  = (__bf16*)(ws + 104440320);      // 73,728
    float*  b768= (float*) (ws + 104514048);      // 3,072
    float*  pb  = (float*) (ws + 104517120);      // 768

    biash_k<<<216, 256, 0, stream>>>(rpi, btab, BTh);
    mask_k<<<41, 256, 0, stream>>>(MT);
    wtrans_k<<<724, 256, 0, stream>>>(q_w, g_w, kv_w, p_w, q_b, g_b, kv_b, p_b,
                                      Wt, Wp, b768, pb);
    padfill_k<<<984, 256, 0, stream>>>(kv_b, KVb);
    gemm_f_k<<<9600, 256, 0, stream>>>(x, Wt, b768, Qb, Gb, KVb);
    attn7_k<<<1200, 512, 0, stream>>>(Qb, KVb, Gb, BTh, MT, Yb);
    gemm_p_k<<<2400, 256, 0, stream>>>(Yb, Wp, pb, out);
}